// Round 16
// baseline (174.649 us; speedup 1.0000x reference)
//
#include <hip/hip_runtime.h>
#include <math.h>

#ifndef M_PI
#define M_PI 3.14159265358979323846
#endif

// Problem constants
#define HH 192
#define WW 192
#define CC 16
#define FF 32
#define BB 8
#define NBI 68        // active frequency box per spatial axis (freqs -34..33)
#define NROW 35       // computed H-spectrum rows: s = 0..34 (rest by conj symmetry)
#define NCOL 69       // computed W-spectrum cols: sj = -34..34 (col = sj+34)
#define ROW0 62       // first centered (pre-fftshift) row of the mask box
#define MASK_T 4560   // (2i-191)^2 + (2j-191)^2 <= 4560  <=>  d/dmax < 0.25 (exact)
#define NWC (WW*CC)   // 3072
#define SCALE (1.0f/1179648.0f)   // 1/(192*192*32) ifft normalization
#define NDFTH 576     // dft_h blocks in k_front (first in grid: longest-job-first)

// Workspace layout (bytes). ws_size = 256 MiB; fully de-aliased.
// Peak = 71,388,160 B.
#define OFF_KQ   4096ull        // 68*68*16*32 float2 = 18,939,904 -> ends 18,944,000
#define OFF_T1   18944000ull    // 2 * 8*35*3072 float2 = 13,762,560 -> ends 32,706,560
#define OFF_T2   32706560ull    // 8*35*69*16 float2 = 2,472,960 -> ends 35,179,520
#define OFF_M2   35179520ull    // 8*68*68*32 float2 = 9,469,952 -> ends 44,649,472
#define OFF_M3   44649472ull    // 8*192*68*32 float2 = 26,738,688 -> ends 71,388,160
#define T1PART   (BB*NROW*NWC)  // float2 elems per h-quad partial (860,160)

__device__ __forceinline__ float2 cmul(float2 a, float2 b) {
    return make_float2(a.x*b.x - a.y*b.y, a.x*b.y + a.y*b.x);
}

// Build the 192-root twiddle table in LDS: tl[t] = e^{+2pi i t/192}.
// Table error ~1e-7 (sincosf) — negligible vs fp32 recurrence error.
__device__ __forceinline__ void build_twiddles(float2* tl, int tid) {
    if (tid < 192) {
        float th = (float)(2.0 * M_PI / 192.0) * (float)tid;
        float s, c;
        sincosf(th, &s, &c);
        tl[tid] = make_float2(c, s);
    }
}

// K_FRONT: concatenated grid — blocks [0, NDFTH) do the partial forward DFT
// over H (radix-4, 12 rows x 1 wc per thread: input re-read factor 3 instead
// of 9); blocks [NDFTH, +68*68) densify the weights into KQ. Long dft_h
// blocks go FIRST (longest-job-first + they feed k_dft_w).
__global__ __launch_bounds__(256) void k_front(
        const float* __restrict__ in, const float* __restrict__ kr,
        const float* __restrict__ ki, float2* __restrict__ KQ,
        float2* __restrict__ T1) {
    int tid = threadIdx.x;
    __shared__ float2 tl[192];
    build_twiddles(tl, tid);
    __syncthreads();

    if (blockIdx.x < NDFTH) {
        // ---- dft_h (radix-4 over h): T1(s) = sum_{h<48} v_{s mod 4}(h) e^{-2pi i s h/192}
        // 12 rows x 1 wc per thread. class(row) = row mod 4 = u mod 4 (12 ≡ 0 mod 4).
        int idx = blockIdx.x;             // 0..575
        int b   = idx / 72;
        int rem = idx - b*72;
        int rg  = rem / 24;               // 0..2 -> rows rg*12 .. rg*12+11
        int rem2 = rem - rg*24;
        int chunk = rem2 >> 1;            // 0..11 (wc chunk of 256)
        int part  = rem2 & 1;
        int h0 = part * 24;
        const float* inb = in + (size_t)b * HH * NWC;
        int wc0 = chunk*256 + tid;
        float2 tw[12], r[12], acc[12];
        #pragma unroll
        for (int u = 0; u < 12; u++) {
            int row = rg*12 + u;
            int s = row < NROW ? row : 0;
            float2 tv = tl[s];
            r[u] = make_float2(tv.x, -tv.y);          // e^{-2pi i s/192}
            float2 t0 = tl[(s*h0) % 192];
            tw[u] = make_float2(t0.x, -t0.y);         // e^{-2pi i s h0/192}
            acc[u] = make_float2(0.f, 0.f);
        }
        for (int h = h0; h < h0 + 24; h++) {
            const float* p0 = inb + (size_t)h * NWC + wc0;
            float a = p0[0];
            float e = p0[48*NWC];
            float c = p0[96*NWC];
            float d = p0[144*NWC];
            float t0 = a + c, t1 = e + d, t2 = a - c, t3 = e - d;
            float v0 = t0 + t1, v2 = t0 - t1;
            #pragma unroll
            for (int u = 0; u < 12; u++) {
                int cls = u & 3;
                if (cls == 0)      { acc[u].x += v0*tw[u].x;              acc[u].y += v0*tw[u].y; }
                else if (cls == 1) { acc[u].x += t2*tw[u].x + t3*tw[u].y; acc[u].y += t2*tw[u].y - t3*tw[u].x; }
                else if (cls == 2) { acc[u].x += v2*tw[u].x;              acc[u].y += v2*tw[u].y; }
                else               { acc[u].x += t2*tw[u].x - t3*tw[u].y; acc[u].y += t2*tw[u].y + t3*tw[u].x; }
                tw[u] = cmul(tw[u], r[u]);
            }
        }
        #pragma unroll
        for (int u = 0; u < 12; u++) {
            int row = rg*12 + u;
            if (row < NROW)
                T1[(size_t)part * T1PART + ((size_t)(b*NROW + row)) * NWC + wc0] = acc[u];
        }
    } else {
        // ---- densify: KQ[c,g] = sum_{sc,f} e^{-2pi i c sc/16} K[sc,f] e^{+2pi i f g/32}
        int blk = blockIdx.x - NDFTH;         // bi*68 + bj
        int bi = blk / NBI, bj = blk - bi*NBI;
        float2* KQo = KQ + (size_t)blk * (CC*FF);
        int a = 2*(ROW0+bi) - 191;
        int bc = 2*(ROW0+bj) - 191;
        bool masked = (a*a + bc*bc) <= MASK_T;   // block-uniform
        if (!masked) {
            for (int e = tid; e < CC*FF; e += 256) KQo[e] = make_float2(0.f, 0.f);
            return;
        }
        __shared__ float2 Kc[CC][FF+1];
        __shared__ float2 Kt[CC][FF+1];
        __shared__ int cnts[NBI];
        __shared__ int rank_s;
        if (tid < NBI) {        // per-row masked-count (exact integer sqrt)
            int ii = ROW0 + tid;
            int aa = 2*ii - 191;
            int rem = MASK_T - aa*aa;
            int q = (int)sqrtf((float)rem);
            while ((q+1)*(q+1) <= rem) q++;
            while (q > 0 && q*q > rem) q--;
            cnts[tid] = ((191 + q) >> 1) - ((192 - q) >> 1) + 1;
        }
        __syncthreads();
        if (tid == 0) {         // rank = prefix(cnts)[bi] + (ROW0+bj) - jmin[bi]
            int acc = 0;
            for (int i = 0; i < bi; i++) acc += cnts[i];
            int ii = ROW0 + bi;
            int aa = 2*ii - 191;
            int rem = MASK_T - aa*aa;
            int q = (int)sqrtf((float)rem);
            while ((q+1)*(q+1) <= rem) q++;
            while (q > 0 && q*q > rem) q--;
            rank_s = acc + (ROW0 + bj) - ((192 - q) >> 1);
        }
        __syncthreads();
        size_t base = (size_t)rank_s * (CC*FF);
        for (int e = tid; e < CC*FF; e += 256)
            Kc[e>>5][e&31] = make_float2(kr[base+e], ki[base+e]);
        __syncthreads();
        for (int e = tid; e < CC*FF; e += 256) {      // Kt[cp][f] = DFT16_c
            int cp = e >> 5, f = e & 31;
            float2 acc = make_float2(0.f, 0.f);
            #pragma unroll
            for (int c = 0; c < CC; c++) {
                int tt = (12*c*cp) % 192;             // 2pi/16 = 2pi*12/192
                float2 w = tl[tt];
                float2 v = Kc[c][f];
                acc.x += v.x*w.x + v.y*w.y;           // v * conj(w)
                acc.y += v.y*w.x - v.x*w.y;
            }
            Kt[cp][f] = acc;
        }
        __syncthreads();
        for (int e = tid; e < CC*FF; e += 256) {      // KQ[cp][g] = iDFT32_f
            int cp = e >> 5, g = e & 31;
            float2 acc = make_float2(0.f, 0.f);
            #pragma unroll
            for (int f = 0; f < FF; f++) {
                int tt = (6*f*g) % 192;               // 2pi/32 = 2pi*6/192
                float2 w = tl[tt];
                float2 v = Kt[cp][f];
                acc.x += v.x*w.x - v.y*w.y;           // v * w
                acc.y += v.x*w.y + v.y*w.x;
            }
            KQo[cp*FF + g] = acc;
        }
    }
}

// K_B: partial forward DFT over W, radix-2 over w:
// T2(col) = sum_{w=0}^{95} (S[w] +- S[w+96]) e^{-2pi i sj w/192}, class by parity(sj).
// Column dim split 4-ways across blockIdx.z for occupancy.
__global__ __launch_bounds__(256) void k_dft_w(
        const float2* __restrict__ T1, float2* __restrict__ T2) {
    int row = blockIdx.x;             // 0..34
    int b   = blockIdx.y;
    int q   = blockIdx.z;             // col quarter: bases 0,17,35,52
    const int qbase[4] = {0, 17, 35, 52};
    const int qcnt[4]  = {17, 18, 17, 17};
    int base = qbase[q], cnt = qcnt[q];
    int tid = threadIdx.x;
    __shared__ float2 tl[192];
    __shared__ float2 shp[96][CC];    // 12 KB  (S[w] + S[w+96])
    __shared__ float2 shm[96][CC];    // 12 KB  (S[w] - S[w+96])
    build_twiddles(tl, tid);
    const float2* src = T1 + ((size_t)(b*NROW + row)) * NWC;
    for (int e = tid; e < 96*CC; e += 256) {
        float2 a0 = src[e];
        float2 a1 = src[e + T1PART];
        float2 b0 = src[e + 96*CC];
        float2 b1 = src[e + 96*CC + T1PART];
        float Sx = a0.x + a1.x, Sy = a0.y + a1.y;
        float Tx = b0.x + b1.x, Ty = b0.y + b1.y;
        shp[e>>4][e&15] = make_float2(Sx + Tx, Sy + Ty);
        shm[e>>4][e&15] = make_float2(Sx - Tx, Sy - Ty);
    }
    __syncthreads();
    int c = tid >> 4;                 // 0..15
    int bjL = tid & 15;               // 0..15
    // parity(col) = (base + bjL + 16k)&1 = (base + bjL)&1 (constant over k)
    const float2* shsel = ((base + bjL) & 1) ? &shm[0][0] : &shp[0][0];
    float2 tw[2], r[2], acc[2];
    #pragma unroll
    for (int k = 0; k < 2; k++) {
        int off = bjL + 16*k;
        int col = base + off;
        bool valid = off < cnt;
        int sj = (valid ? col : 34) - 34;
        tw[k] = make_float2(1.f, 0.f);
        acc[k] = make_float2(0.f, 0.f);
        int ts = ((sj % 192) + 192) % 192;
        float2 tv = tl[ts];
        r[k] = make_float2(tv.x, -tv.y);
    }
    for (int w = 0; w < 96; w++) {
        float2 av = shsel[w*CC + c];
        #pragma unroll
        for (int k = 0; k < 2; k++) {
            acc[k].x += av.x*tw[k].x - av.y*tw[k].y;
            acc[k].y += av.x*tw[k].y + av.y*tw[k].x;
            tw[k] = cmul(tw[k], r[k]);
        }
    }
    float2* dst = T2 + ((size_t)((b*NROW + row)*NCOL)) * CC;
    #pragma unroll
    for (int k = 0; k < 2; k++) {
        int off = bjL + 16*k;
        int col = base + off;
        if (off < cnt) dst[col*CC + c] = acc[k];
    }
}

// K_M: per-site 16->32 complex matvec; negative-s rows read the conj mirror.
__global__ __launch_bounds__(256) void k_mix(
        const float2* __restrict__ T2, const float2* __restrict__ KQ,
        float2* __restrict__ M2) {
    int site = blockIdx.x;            // bi*68 + bj
    int bi = site / NBI, bj = site - bi*NBI;
    int tid = threadIdx.x;
    int b = tid >> 5;                 // 8 groups of 32 lanes
    int g = tid & 31;
    int row, col;
    bool cj;
    if (bi >= 34) { row = bi - 34; col = bj;      cj = false; }
    else          { row = 34 - bi; col = 68 - bj; cj = true;  }
    const float2* x  = T2 + ((size_t)(b*NROW + row) * NCOL + col) * CC;
    const float2* kq = KQ + (size_t)site * (CC*FF);
    float sgn = cj ? -1.f : 1.f;
    float2 acc = make_float2(0.f, 0.f);
    #pragma unroll
    for (int cp = 0; cp < CC; cp++) {
        float2 xv = x[cp];
        xv.y *= sgn;
        float2 kv = kq[cp*FF + g];
        acc.x += xv.x*kv.x - xv.y*kv.y;
        acc.y += xv.x*kv.y + xv.y*kv.x;
    }
    M2[((size_t)b * (NBI*NBI) + site) * FF + g] = acc;
}

// K_E2: inverse DFT over W — LDS-broadcast + RADIX-4 over y.
// Classes m = (bj-34) mod 4:  M3(y+48k) = sum_m i^{mk} S_m(y), where
// S_m = sum_{bj in class m} m2[bj] e^{+2pi i (bj-34) y/192}.
// M3 layout [b][y][bi][g] (y outermost) so k_idft_h reads contiguously.
__global__ __launch_bounds__(192) void k_idft_w(
        const float2* __restrict__ M2, float2* __restrict__ M3) {
    int bi = blockIdx.x;
    int b  = blockIdx.y;
    int z  = blockIdx.z;                 // y zone: 0 or 1
    int tid = threadIdx.x;
    int gq = tid & 7;                    // 0..7
    int ty = tid >> 3;                   // 0..23
    int g0 = gq * 4;
    int y  = z*24 + ty;                  // [0,48)
    __shared__ float2 tl[192];
    __shared__ __align__(16) float2 m2s[NBI][FF];   // 17.4 KB
    build_twiddles(tl, tid);
    {
        const float4* src = reinterpret_cast<const float4*>(
            M2 + ((size_t)b*(NBI*NBI) + (size_t)bi*NBI) * FF);
        float4* dst = reinterpret_cast<float4*>(&m2s[0][0]);
        for (int e = tid; e < NBI*FF/2; e += 192) dst[e] = src[e];
    }
    __syncthreads();
    float2 tw = tl[(158*y) % 192];       // e^{+2pi i (-34) y/192}
    float2 rr = tl[y];                   // e^{+2pi i y/192}
    float2 zz = make_float2(0.f, 0.f);
    float2 C0[4] = {zz,zz,zz,zz};        // class 0: bj-34 ≡ 0 (mod 4)
    float2 C1[4] = {zz,zz,zz,zz};
    float2 C2[4] = {zz,zz,zz,zz};
    float2 C3[4] = {zz,zz,zz,zz};
#define IW_STEP(ROW, CL) { \
    float4 e0 = *reinterpret_cast<const float4*>(&m2s[ROW][g0]); \
    float4 e1 = *reinterpret_cast<const float4*>(&m2s[ROW][g0+2]); \
    CL[0].x += e0.x*tw.x - e0.y*tw.y;  CL[0].y += e0.x*tw.y + e0.y*tw.x; \
    CL[1].x += e0.z*tw.x - e0.w*tw.y;  CL[1].y += e0.z*tw.y + e0.w*tw.x; \
    CL[2].x += e1.x*tw.x - e1.y*tw.y;  CL[2].y += e1.x*tw.y + e1.y*tw.x; \
    CL[3].x += e1.z*tw.x - e1.w*tw.y;  CL[3].y += e1.z*tw.y + e1.w*tw.x; \
    tw = cmul(tw, rr); }
    for (int bj = 0; bj < NBI; bj += 4) {
        // bj-34 mod 4: bj+0 -> 2, bj+1 -> 3, bj+2 -> 0, bj+3 -> 1
        IW_STEP(bj,   C2)
        IW_STEP(bj+1, C3)
        IW_STEP(bj+2, C0)
        IW_STEP(bj+3, C1)
    }
#undef IW_STEP
    // Combine: out(y+48k) = sum_m i^{mk} C_m
    float2 R0[4], R1[4], R2[4], R3[4];
    #pragma unroll
    for (int k = 0; k < 4; k++) {
        float2 p = make_float2(C0[k].x + C2[k].x, C0[k].y + C2[k].y);
        float2 q = make_float2(C1[k].x + C3[k].x, C1[k].y + C3[k].y);
        float2 m = make_float2(C0[k].x - C2[k].x, C0[k].y - C2[k].y);
        float2 n = make_float2(C1[k].x - C3[k].x, C1[k].y - C3[k].y);
        R0[k] = make_float2(p.x + q.x, p.y + q.y);        // y
        R2[k] = make_float2(p.x - q.x, p.y - q.y);        // y+96
        R1[k] = make_float2(m.x - n.y, m.y + n.x);        // y+48  (m + i n)
        R3[k] = make_float2(m.x + n.y, m.y - n.x);        // y+144 (m - i n)
    }
    // M3[b][y][bi][g]
    float2* p0 = M3 + (((size_t)b*HH + y)*NBI + bi)*FF + g0;
    *reinterpret_cast<float4*>(p0)     = make_float4(R0[0].x,R0[0].y,R0[1].x,R0[1].y);
    *reinterpret_cast<float4*>(p0 + 2) = make_float4(R0[2].x,R0[2].y,R0[3].x,R0[3].y);
    float2* p1 = M3 + (((size_t)b*HH + y + 48)*NBI + bi)*FF + g0;
    *reinterpret_cast<float4*>(p1)     = make_float4(R1[0].x,R1[0].y,R1[1].x,R1[1].y);
    *reinterpret_cast<float4*>(p1 + 2) = make_float4(R1[2].x,R1[2].y,R1[3].x,R1[3].y);
    float2* p2 = M3 + (((size_t)b*HH + y + 96)*NBI + bi)*FF + g0;
    *reinterpret_cast<float4*>(p2)     = make_float4(R2[0].x,R2[0].y,R2[1].x,R2[1].y);
    *reinterpret_cast<float4*>(p2 + 2) = make_float4(R2[2].x,R2[2].y,R2[3].x,R2[3].y);
    float2* p3 = M3 + (((size_t)b*HH + y + 144)*NBI + bi)*FF + g0;
    *reinterpret_cast<float4*>(p3)     = make_float4(R3[0].x,R3[0].y,R3[1].x,R3[1].y);
    *reinterpret_cast<float4*>(p3 + 2) = make_float4(R3[2].x,R3[2].y,R3[3].x,R3[3].y);
}

// K_E3: inverse DFT over H keeping Re only, Hermitian (s,-s) pairing AND
// radix-2 over x: even/odd-p accumulators give out(x) = E+O, out(x+96) = E-O.
// comb[p][g] = (A,B):  contribution = A*cos(2pi p x/192) - B*sin(...).
// M3 layout [b][y][bi][g]: this block's slice is one contiguous 17.4 KB read.
__global__ __launch_bounds__(256) void k_idft_h(
        const float2* __restrict__ M3, float* __restrict__ out) {
    int y = blockIdx.x;
    int b = blockIdx.y;
    int tid = threadIdx.x;
    const float2* m3s = M3 + ((size_t)b*HH + y)*NBI*FF;   // [bi][g] slice
    __shared__ float2 tl[192];
    __shared__ __align__(16) float2 comb[NROW][FF];   // (A,B) per pair, 8.96 KB
    build_twiddles(tl, tid);
    for (int e = tid; e < NROW*FF; e += 256) {
        int p = e >> 5, g = e & 31;
        float A, Bv;
        if (p == 0) {
            float2 v = m3s[34*FF + g];
            A = v.x; Bv = 0.f;
        } else if (p == 34) {
            float2 v = m3s[0*FF + g];
            A = v.x; Bv = -v.y;
        } else {
            float2 vp = m3s[(34 + p)*FF + g];
            float2 vm = m3s[(34 - p)*FF + g];
            A = vp.x + vm.x; Bv = vp.y - vm.y;
        }
        comb[p][g] = make_float2(A, Bv);
    }
    __syncthreads();
    int tx = tid >> 3;          // 0..31  (3 x-pairs per thread: x = tx*3+j)
    int tg = tid & 7;
    int g0 = tg * 4;
    float2 tw[3], rr[3];
    float ae[3][4], ao[3][4];
    #pragma unroll
    for (int j = 0; j < 3; j++) {
        int x = tx*3 + j;
        tw[j] = make_float2(1.f, 0.f);   // angle p=0
        rr[j] = tl[x];                   // e^{+2pi i x/192} per p step
        #pragma unroll
        for (int q = 0; q < 4; q++) { ae[j][q] = 0.f; ao[j][q] = 0.f; }
    }
    for (int p = 0; p < 34; p += 2) {
        float4 f0 = *reinterpret_cast<const float4*>(&comb[p][g0]);     // A0,B0,A1,B1
        float4 f1 = *reinterpret_cast<const float4*>(&comb[p][g0+2]);   // A2,B2,A3,B3
        #pragma unroll
        for (int j = 0; j < 3; j++) {
            float2 t = tw[j];
            ae[j][0] += f0.x*t.x - f0.y*t.y;
            ae[j][1] += f0.z*t.x - f0.w*t.y;
            ae[j][2] += f1.x*t.x - f1.y*t.y;
            ae[j][3] += f1.z*t.x - f1.w*t.y;
            tw[j] = cmul(t, rr[j]);
        }
        float4 h0 = *reinterpret_cast<const float4*>(&comb[p+1][g0]);
        float4 h1 = *reinterpret_cast<const float4*>(&comb[p+1][g0+2]);
        #pragma unroll
        for (int j = 0; j < 3; j++) {
            float2 t = tw[j];
            ao[j][0] += h0.x*t.x - h0.y*t.y;
            ao[j][1] += h0.z*t.x - h0.w*t.y;
            ao[j][2] += h1.x*t.x - h1.y*t.y;
            ao[j][3] += h1.z*t.x - h1.w*t.y;
            tw[j] = cmul(t, rr[j]);
        }
    }
    {   // tail p = 34 (even)
        float4 f0 = *reinterpret_cast<const float4*>(&comb[34][g0]);
        float4 f1 = *reinterpret_cast<const float4*>(&comb[34][g0+2]);
        #pragma unroll
        for (int j = 0; j < 3; j++) {
            float2 t = tw[j];
            ae[j][0] += f0.x*t.x - f0.y*t.y;
            ae[j][1] += f0.z*t.x - f0.w*t.y;
            ae[j][2] += f1.x*t.x - f1.y*t.y;
            ae[j][3] += f1.z*t.x - f1.w*t.y;
        }
    }
    #pragma unroll
    for (int j = 0; j < 3; j++) {
        int x = tx*3 + j;
        float4 oA, oB;
        oA.x = (ae[j][0]+ao[j][0])*SCALE; oA.y = (ae[j][1]+ao[j][1])*SCALE;
        oA.z = (ae[j][2]+ao[j][2])*SCALE; oA.w = (ae[j][3]+ao[j][3])*SCALE;
        oB.x = (ae[j][0]-ao[j][0])*SCALE; oB.y = (ae[j][1]-ao[j][1])*SCALE;
        oB.z = (ae[j][2]-ao[j][2])*SCALE; oB.w = (ae[j][3]-ao[j][3])*SCALE;
        *reinterpret_cast<float4*>(&out[(((size_t)(b*HH + x)) * WW + y) * FF + g0]) = oA;
        *reinterpret_cast<float4*>(&out[(((size_t)(b*HH + x + 96)) * WW + y) * FF + g0]) = oB;
    }
}

extern "C" void kernel_launch(void* const* d_in, const int* in_sizes, int n_in,
                              void* d_out, int out_size, void* d_ws, size_t ws_size,
                              hipStream_t stream) {
    const float* in = (const float*)d_in[0];
    const float* kr = (const float*)d_in[1];
    const float* ki = (const float*)d_in[2];
    float* out = (float*)d_out;
    char* ws = (char*)d_ws;
    float2* KQ  = (float2*)(ws + OFF_KQ);
    float2* T1  = (float2*)(ws + OFF_T1);
    float2* T2  = (float2*)(ws + OFF_T2);
    float2* M2  = (float2*)(ws + OFF_M2);
    float2* M3  = (float2*)(ws + OFF_M3);

    k_front <<<dim3(NDFTH + NBI*NBI), 256, 0, stream>>>(in, kr, ki, KQ, T1);
    k_dft_w <<<dim3(NROW, BB, 4), 256, 0, stream>>>(T1, T2);
    k_mix   <<<NBI*NBI, 256, 0, stream>>>(T2, KQ, M2);
    k_idft_w<<<dim3(NBI, BB, 2), 192, 0, stream>>>(M2, M3);
    k_idft_h<<<dim3(HH, BB), 256, 0, stream>>>(M3, out);
}

// Round 17
// 129.286 us; speedup vs baseline: 1.3509x; 1.3509x over previous
//
#include <hip/hip_runtime.h>
#include <math.h>

#ifndef M_PI
#define M_PI 3.14159265358979323846
#endif

// Problem constants
#define HH 192
#define WW 192
#define CC 16
#define FF 32
#define BB 8
#define NBI 68        // active frequency box per spatial axis (freqs -34..33)
#define NROW 35       // computed H-spectrum rows: s = 0..34 (rest by conj symmetry)
#define NCOL 69       // computed W-spectrum cols: sj = -34..34 (col = sj+34)
#define ROW0 62       // first centered (pre-fftshift) row of the mask box
#define MASK_T 4560   // (2i-191)^2 + (2j-191)^2 <= 4560  <=>  d/dmax < 0.25 (exact)
#define NWC (WW*CC)   // 3072
#define SCALE (1.0f/1179648.0f)   // 1/(192*192*32) ifft normalization

// Workspace layout (bytes). ws_size = 256 MiB; fully de-aliased.
// Peak = 71,388,160 B.
#define OFF_KQ   4096ull        // 68*68*16*32 float2 = 18,939,904 -> ends 18,944,000
#define OFF_T1   18944000ull    // 2 * 8*35*3072 float2 = 13,762,560 -> ends 32,706,560
#define OFF_T2   32706560ull    // 8*35*69*16 float2 = 2,472,960 -> ends 35,179,520
#define OFF_M2   35179520ull    // 8*68*68*32 float2 = 9,469,952 -> ends 44,649,472
#define OFF_M3   44649472ull    // 8*192*68*32 float2 = 26,738,688 -> ends 71,388,160
#define T1PART   (BB*NROW*NWC)  // float2 elems per h-quad partial (860,160)

__device__ __forceinline__ float2 cmul(float2 a, float2 b) {
    return make_float2(a.x*b.x - a.y*b.y, a.x*b.y + a.y*b.x);
}

// Build the 192-root twiddle table in LDS: tl[t] = e^{+2pi i t/192}.
// Table error ~1e-7 (sincosf) — negligible vs fp32 recurrence error.
__device__ __forceinline__ void build_twiddles(float2* tl, int tid) {
    if (tid < 192) {
        float th = (float)(2.0 * M_PI / 192.0) * (float)tid;
        float s, c;
        sincosf(th, &s, &c);
        tl[tid] = make_float2(c, s);
    }
}

// K_FRONT (r15 form, VGPR 64): blocks [0, 68*68) densify the weights into KQ
// (with the C-forward-DFT and F-inverse-DFT folded in), blocks [68*68, +576)
// do the partial forward DFT over H (radix-4, 4 rows x 3 wc per thread).
__global__ __launch_bounds__(256) void k_front(
        const float* __restrict__ in, const float* __restrict__ kr,
        const float* __restrict__ ki, float2* __restrict__ KQ,
        float2* __restrict__ T1) {
    int tid = threadIdx.x;
    __shared__ float2 tl[192];
    build_twiddles(tl, tid);
    __syncthreads();

    if (blockIdx.x < NBI*NBI) {
        // ---- densify: KQ[c,g] = sum_{sc,f} e^{-2pi i c sc/16} K[sc,f] e^{+2pi i f g/32}
        int blk = blockIdx.x;                 // bi*68 + bj
        int bi = blk / NBI, bj = blk - bi*NBI;
        float2* KQo = KQ + (size_t)blk * (CC*FF);
        int a = 2*(ROW0+bi) - 191;
        int bc = 2*(ROW0+bj) - 191;
        bool masked = (a*a + bc*bc) <= MASK_T;   // block-uniform
        if (!masked) {
            for (int e = tid; e < CC*FF; e += 256) KQo[e] = make_float2(0.f, 0.f);
            return;
        }
        __shared__ float2 Kc[CC][FF+1];
        __shared__ float2 Kt[CC][FF+1];
        __shared__ int cnts[NBI];
        __shared__ int rank_s;
        if (tid < NBI) {        // per-row masked-count (exact integer sqrt)
            int ii = ROW0 + tid;
            int aa = 2*ii - 191;
            int rem = MASK_T - aa*aa;
            int q = (int)sqrtf((float)rem);
            while ((q+1)*(q+1) <= rem) q++;
            while (q > 0 && q*q > rem) q--;
            cnts[tid] = ((191 + q) >> 1) - ((192 - q) >> 1) + 1;
        }
        __syncthreads();
        if (tid == 0) {         // rank = prefix(cnts)[bi] + (ROW0+bj) - jmin[bi]
            int acc = 0;
            for (int i = 0; i < bi; i++) acc += cnts[i];
            int ii = ROW0 + bi;
            int aa = 2*ii - 191;
            int rem = MASK_T - aa*aa;
            int q = (int)sqrtf((float)rem);
            while ((q+1)*(q+1) <= rem) q++;
            while (q > 0 && q*q > rem) q--;
            rank_s = acc + (ROW0 + bj) - ((192 - q) >> 1);
        }
        __syncthreads();
        size_t base = (size_t)rank_s * (CC*FF);
        for (int e = tid; e < CC*FF; e += 256)
            Kc[e>>5][e&31] = make_float2(kr[base+e], ki[base+e]);
        __syncthreads();
        for (int e = tid; e < CC*FF; e += 256) {      // Kt[cp][f] = DFT16_c
            int cp = e >> 5, f = e & 31;
            float2 acc = make_float2(0.f, 0.f);
            #pragma unroll
            for (int c = 0; c < CC; c++) {
                int tt = (12*c*cp) % 192;             // 2pi/16 = 2pi*12/192
                float2 w = tl[tt];
                float2 v = Kc[c][f];
                acc.x += v.x*w.x + v.y*w.y;           // v * conj(w)
                acc.y += v.y*w.x - v.x*w.y;
            }
            Kt[cp][f] = acc;
        }
        __syncthreads();
        for (int e = tid; e < CC*FF; e += 256) {      // KQ[cp][g] = iDFT32_f
            int cp = e >> 5, g = e & 31;
            float2 acc = make_float2(0.f, 0.f);
            #pragma unroll
            for (int f = 0; f < FF; f++) {
                int tt = (6*f*g) % 192;               // 2pi/32 = 2pi*6/192
                float2 w = tl[tt];
                float2 v = Kt[cp][f];
                acc.x += v.x*w.x - v.y*w.y;           // v * w
                acc.y += v.x*w.y + v.y*w.x;
            }
            KQo[cp*FF + g] = acc;
        }
    } else {
        // ---- dft_h (radix-4 over h): T1(s) = sum_{h<48} v_{s mod 4}(h) e^{-2pi i s h/192}
        int idx = blockIdx.x - NBI*NBI;   // 0..575
        int b   = idx / 72;
        int rem = idx - b*72;
        int bg  = rem >> 3;               // 0..8, 4 rows each
        int zc  = rem & 7;                // quarter*2 + part
        int z   = zc >> 1;
        int part = zc & 1;
        int h0 = part * 24;
        const float* inb = in + (size_t)b * HH * NWC;
        int wc0 = z * 768 + tid;
        float2 tw[4], r[4];
        #pragma unroll
        for (int u = 0; u < 4; u++) {
            int row = bg*4 + u;
            int s = row < NROW ? row : 0;
            float2 tv = tl[s];
            r[u] = make_float2(tv.x, -tv.y);          // e^{-2pi i s/192}
            float2 t0 = tl[(s*h0) % 192];
            tw[u] = make_float2(t0.x, -t0.y);         // e^{-2pi i s h0/192}
        }
        float2 acc[4][3];
        #pragma unroll
        for (int u = 0; u < 4; u++)
            #pragma unroll
            for (int k = 0; k < 3; k++) acc[u][k] = make_float2(0.f, 0.f);
        for (int h = h0; h < h0 + 24; h++) {
            const float* p0 = inb + (size_t)h * NWC + wc0;
            const float* p1 = p0 + 48*NWC;
            const float* p2 = p0 + 96*NWC;
            const float* p3 = p0 + 144*NWC;
            float a0=p0[0], a1=p0[256], a2=p0[512];
            float e0=p1[0], e1=p1[256], e2=p1[512];
            float c0=p2[0], c1=p2[256], c2=p2[512];
            float d0=p3[0], d1=p3[256], d2=p3[512];
            float t0_0=a0+c0, t1_0=e0+d0, t2_0=a0-c0, t3_0=e0-d0;
            float t0_1=a1+c1, t1_1=e1+d1, t2_1=a1-c1, t3_1=e1-d1;
            float t0_2=a2+c2, t1_2=e2+d2, t2_2=a2-c2, t3_2=e2-d2;
            float v0_0=t0_0+t1_0, v2_0=t0_0-t1_0;
            float v0_1=t0_1+t1_1, v2_1=t0_1-t1_1;
            float v0_2=t0_2+t1_2, v2_2=t0_2-t1_2;
            // u=0: v0 real
            acc[0][0].x += v0_0*tw[0].x; acc[0][0].y += v0_0*tw[0].y;
            acc[0][1].x += v0_1*tw[0].x; acc[0][1].y += v0_1*tw[0].y;
            acc[0][2].x += v0_2*tw[0].x; acc[0][2].y += v0_2*tw[0].y;
            tw[0] = cmul(tw[0], r[0]);
            // u=1: v1 = (t2, -t3)
            acc[1][0].x += t2_0*tw[1].x + t3_0*tw[1].y; acc[1][0].y += t2_0*tw[1].y - t3_0*tw[1].x;
            acc[1][1].x += t2_1*tw[1].x + t3_1*tw[1].y; acc[1][1].y += t2_1*tw[1].y - t3_1*tw[1].x;
            acc[1][2].x += t2_2*tw[1].x + t3_2*tw[1].y; acc[1][2].y += t2_2*tw[1].y - t3_2*tw[1].x;
            tw[1] = cmul(tw[1], r[1]);
            // u=2: v2 real
            acc[2][0].x += v2_0*tw[2].x; acc[2][0].y += v2_0*tw[2].y;
            acc[2][1].x += v2_1*tw[2].x; acc[2][1].y += v2_1*tw[2].y;
            acc[2][2].x += v2_2*tw[2].x; acc[2][2].y += v2_2*tw[2].y;
            tw[2] = cmul(tw[2], r[2]);
            // u=3: v3 = (t2, t3)
            acc[3][0].x += t2_0*tw[3].x - t3_0*tw[3].y; acc[3][0].y += t2_0*tw[3].y + t3_0*tw[3].x;
            acc[3][1].x += t2_1*tw[3].x - t3_1*tw[3].y; acc[3][1].y += t2_1*tw[3].y + t3_1*tw[3].x;
            acc[3][2].x += t2_2*tw[3].x - t3_2*tw[3].y; acc[3][2].y += t2_2*tw[3].y + t3_2*tw[3].x;
            tw[3] = cmul(tw[3], r[3]);
        }
        #pragma unroll
        for (int u = 0; u < 4; u++) {
            int row = bg*4 + u;
            if (row < NROW) {
                float2* o = T1 + (size_t)part * T1PART + ((size_t)(b*NROW + row)) * NWC + wc0;
                o[0] = acc[u][0]; o[256] = acc[u][1]; o[512] = acc[u][2];
            }
        }
    }
}

// K_B: partial forward DFT over W, radix-2 over w:
// T2(col) = sum_{w=0}^{95} (S[w] +- S[w+96]) e^{-2pi i sj w/192}, class by parity(sj).
// Column dim split 4-ways across blockIdx.z for occupancy.
__global__ __launch_bounds__(256) void k_dft_w(
        const float2* __restrict__ T1, float2* __restrict__ T2) {
    int row = blockIdx.x;             // 0..34
    int b   = blockIdx.y;
    int q   = blockIdx.z;             // col quarter: bases 0,17,35,52
    const int qbase[4] = {0, 17, 35, 52};
    const int qcnt[4]  = {17, 18, 17, 17};
    int base = qbase[q], cnt = qcnt[q];
    int tid = threadIdx.x;
    __shared__ float2 tl[192];
    __shared__ float2 shp[96][CC];    // 12 KB  (S[w] + S[w+96])
    __shared__ float2 shm[96][CC];    // 12 KB  (S[w] - S[w+96])
    build_twiddles(tl, tid);
    const float2* src = T1 + ((size_t)(b*NROW + row)) * NWC;
    for (int e = tid; e < 96*CC; e += 256) {
        float2 a0 = src[e];
        float2 a1 = src[e + T1PART];
        float2 b0 = src[e + 96*CC];
        float2 b1 = src[e + 96*CC + T1PART];
        float Sx = a0.x + a1.x, Sy = a0.y + a1.y;
        float Tx = b0.x + b1.x, Ty = b0.y + b1.y;
        shp[e>>4][e&15] = make_float2(Sx + Tx, Sy + Ty);
        shm[e>>4][e&15] = make_float2(Sx - Tx, Sy - Ty);
    }
    __syncthreads();
    int c = tid >> 4;                 // 0..15
    int bjL = tid & 15;               // 0..15
    // parity(col) = (base + bjL + 16k)&1 = (base + bjL)&1 (constant over k)
    const float2* shsel = ((base + bjL) & 1) ? &shm[0][0] : &shp[0][0];
    float2 tw[2], r[2], acc[2];
    #pragma unroll
    for (int k = 0; k < 2; k++) {
        int off = bjL + 16*k;
        int col = base + off;
        bool valid = off < cnt;
        int sj = (valid ? col : 34) - 34;
        tw[k] = make_float2(1.f, 0.f);
        acc[k] = make_float2(0.f, 0.f);
        int ts = ((sj % 192) + 192) % 192;
        float2 tv = tl[ts];
        r[k] = make_float2(tv.x, -tv.y);
    }
    for (int w = 0; w < 96; w++) {
        float2 av = shsel[w*CC + c];
        #pragma unroll
        for (int k = 0; k < 2; k++) {
            acc[k].x += av.x*tw[k].x - av.y*tw[k].y;
            acc[k].y += av.x*tw[k].y + av.y*tw[k].x;
            tw[k] = cmul(tw[k], r[k]);
        }
    }
    float2* dst = T2 + ((size_t)((b*NROW + row)*NCOL)) * CC;
    #pragma unroll
    for (int k = 0; k < 2; k++) {
        int off = bjL + 16*k;
        int col = base + off;
        if (off < cnt) dst[col*CC + c] = acc[k];
    }
}

// K_M: per-site 16->32 complex matvec; negative-s rows read the conj mirror.
__global__ __launch_bounds__(256) void k_mix(
        const float2* __restrict__ T2, const float2* __restrict__ KQ,
        float2* __restrict__ M2) {
    int site = blockIdx.x;            // bi*68 + bj
    int bi = site / NBI, bj = site - bi*NBI;
    int tid = threadIdx.x;
    int b = tid >> 5;                 // 8 groups of 32 lanes
    int g = tid & 31;
    int row, col;
    bool cj;
    if (bi >= 34) { row = bi - 34; col = bj;      cj = false; }
    else          { row = 34 - bi; col = 68 - bj; cj = true;  }
    const float2* x  = T2 + ((size_t)(b*NROW + row) * NCOL + col) * CC;
    const float2* kq = KQ + (size_t)site * (CC*FF);
    float sgn = cj ? -1.f : 1.f;
    float2 acc = make_float2(0.f, 0.f);
    #pragma unroll
    for (int cp = 0; cp < CC; cp++) {
        float2 xv = x[cp];
        xv.y *= sgn;
        float2 kv = kq[cp*FF + g];
        acc.x += xv.x*kv.x - xv.y*kv.y;
        acc.y += xv.x*kv.y + xv.y*kv.x;
    }
    M2[((size_t)b * (NBI*NBI) + site) * FF + g] = acc;
}

// K_E2: inverse DFT over W — LDS-broadcast + RADIX-4 over y, single-stage.
// One 384-thread block per (bi,b): stages the [68][32] M2 slice ONCE (was
// twice across z=0/1), builds the twiddle table once. Thread = (ty 0..47,
// gq 0..7): y = ty, 4 g, radix-4 classes give y, y+48, y+96, y+144.
// M3 layout [b][y][bi][g] (y outermost) so k_idft_h reads contiguously.
__global__ __launch_bounds__(384) void k_idft_w(
        const float2* __restrict__ M2, float2* __restrict__ M3) {
    int bi = blockIdx.x;
    int b  = blockIdx.y;
    int tid = threadIdx.x;
    int gq = tid & 7;                    // 0..7
    int ty = tid >> 3;                   // 0..47
    int g0 = gq * 4;
    int y  = ty;                         // [0,48)
    __shared__ float2 tl[192];
    __shared__ __align__(16) float2 m2s[NBI][FF];   // 17.4 KB
    build_twiddles(tl, tid);
    {
        const float4* src = reinterpret_cast<const float4*>(
            M2 + ((size_t)b*(NBI*NBI) + (size_t)bi*NBI) * FF);
        float4* dst = reinterpret_cast<float4*>(&m2s[0][0]);
        for (int e = tid; e < NBI*FF/2; e += 384) dst[e] = src[e];
    }
    __syncthreads();
    float2 tw = tl[(158*y) % 192];       // e^{+2pi i (-34) y/192}
    float2 rr = tl[y];                   // e^{+2pi i y/192}
    float2 zz = make_float2(0.f, 0.f);
    float2 C0[4] = {zz,zz,zz,zz};        // class 0: bj-34 ≡ 0 (mod 4)
    float2 C1[4] = {zz,zz,zz,zz};
    float2 C2[4] = {zz,zz,zz,zz};
    float2 C3[4] = {zz,zz,zz,zz};
#define IW_STEP(ROW, CL) { \
    float4 e0 = *reinterpret_cast<const float4*>(&m2s[ROW][g0]); \
    float4 e1 = *reinterpret_cast<const float4*>(&m2s[ROW][g0+2]); \
    CL[0].x += e0.x*tw.x - e0.y*tw.y;  CL[0].y += e0.x*tw.y + e0.y*tw.x; \
    CL[1].x += e0.z*tw.x - e0.w*tw.y;  CL[1].y += e0.z*tw.y + e0.w*tw.x; \
    CL[2].x += e1.x*tw.x - e1.y*tw.y;  CL[2].y += e1.x*tw.y + e1.y*tw.x; \
    CL[3].x += e1.z*tw.x - e1.w*tw.y;  CL[3].y += e1.z*tw.y + e1.w*tw.x; \
    tw = cmul(tw, rr); }
    for (int bj = 0; bj < NBI; bj += 4) {
        // bj-34 mod 4: bj+0 -> 2, bj+1 -> 3, bj+2 -> 0, bj+3 -> 1
        IW_STEP(bj,   C2)
        IW_STEP(bj+1, C3)
        IW_STEP(bj+2, C0)
        IW_STEP(bj+3, C1)
    }
#undef IW_STEP
    // Combine: out(y+48k) = sum_m i^{mk} C_m
    float2 R0[4], R1[4], R2[4], R3[4];
    #pragma unroll
    for (int k = 0; k < 4; k++) {
        float2 p = make_float2(C0[k].x + C2[k].x, C0[k].y + C2[k].y);
        float2 q = make_float2(C1[k].x + C3[k].x, C1[k].y + C3[k].y);
        float2 m = make_float2(C0[k].x - C2[k].x, C0[k].y - C2[k].y);
        float2 n = make_float2(C1[k].x - C3[k].x, C1[k].y - C3[k].y);
        R0[k] = make_float2(p.x + q.x, p.y + q.y);        // y
        R2[k] = make_float2(p.x - q.x, p.y - q.y);        // y+96
        R1[k] = make_float2(m.x - n.y, m.y + n.x);        // y+48  (m + i n)
        R3[k] = make_float2(m.x + n.y, m.y - n.x);        // y+144 (m - i n)
    }
    // M3[b][y][bi][g]
    float2* p0 = M3 + (((size_t)b*HH + y)*NBI + bi)*FF + g0;
    *reinterpret_cast<float4*>(p0)     = make_float4(R0[0].x,R0[0].y,R0[1].x,R0[1].y);
    *reinterpret_cast<float4*>(p0 + 2) = make_float4(R0[2].x,R0[2].y,R0[3].x,R0[3].y);
    float2* p1 = M3 + (((size_t)b*HH + y + 48)*NBI + bi)*FF + g0;
    *reinterpret_cast<float4*>(p1)     = make_float4(R1[0].x,R1[0].y,R1[1].x,R1[1].y);
    *reinterpret_cast<float4*>(p1 + 2) = make_float4(R1[2].x,R1[2].y,R1[3].x,R1[3].y);
    float2* p2 = M3 + (((size_t)b*HH + y + 96)*NBI + bi)*FF + g0;
    *reinterpret_cast<float4*>(p2)     = make_float4(R2[0].x,R2[0].y,R2[1].x,R2[1].y);
    *reinterpret_cast<float4*>(p2 + 2) = make_float4(R2[2].x,R2[2].y,R2[3].x,R2[3].y);
    float2* p3 = M3 + (((size_t)b*HH + y + 144)*NBI + bi)*FF + g0;
    *reinterpret_cast<float4*>(p3)     = make_float4(R3[0].x,R3[0].y,R3[1].x,R3[1].y);
    *reinterpret_cast<float4*>(p3 + 2) = make_float4(R3[2].x,R3[2].y,R3[3].x,R3[3].y);
}

// K_E3: inverse DFT over H keeping Re only, Hermitian (s,-s) pairing AND
// radix-2 over x: even/odd-p accumulators give out(x) = E+O, out(x+96) = E-O.
// comb[p][g] = (A,B):  contribution = A*cos(2pi p x/192) - B*sin(...).
// M3 layout [b][y][bi][g]: this block's slice is one contiguous 17.4 KB read.
__global__ __launch_bounds__(256) void k_idft_h(
        const float2* __restrict__ M3, float* __restrict__ out) {
    int y = blockIdx.x;
    int b = blockIdx.y;
    int tid = threadIdx.x;
    const float2* m3s = M3 + ((size_t)b*HH + y)*NBI*FF;   // [bi][g] slice
    __shared__ float2 tl[192];
    __shared__ __align__(16) float2 comb[NROW][FF];   // (A,B) per pair, 8.96 KB
    build_twiddles(tl, tid);
    for (int e = tid; e < NROW*FF; e += 256) {
        int p = e >> 5, g = e & 31;
        float A, Bv;
        if (p == 0) {
            float2 v = m3s[34*FF + g];
            A = v.x; Bv = 0.f;
        } else if (p == 34) {
            float2 v = m3s[0*FF + g];
            A = v.x; Bv = -v.y;
        } else {
            float2 vp = m3s[(34 + p)*FF + g];
            float2 vm = m3s[(34 - p)*FF + g];
            A = vp.x + vm.x; Bv = vp.y - vm.y;
        }
        comb[p][g] = make_float2(A, Bv);
    }
    __syncthreads();
    int tx = tid >> 3;          // 0..31  (3 x-pairs per thread: x = tx*3+j)
    int tg = tid & 7;
    int g0 = tg * 4;
    float2 tw[3], rr[3];
    float ae[3][4], ao[3][4];
    #pragma unroll
    for (int j = 0; j < 3; j++) {
        int x = tx*3 + j;
        tw[j] = make_float2(1.f, 0.f);   // angle p=0
        rr[j] = tl[x];                   // e^{+2pi i x/192} per p step
        #pragma unroll
        for (int q = 0; q < 4; q++) { ae[j][q] = 0.f; ao[j][q] = 0.f; }
    }
    for (int p = 0; p < 34; p += 2) {
        float4 f0 = *reinterpret_cast<const float4*>(&comb[p][g0]);     // A0,B0,A1,B1
        float4 f1 = *reinterpret_cast<const float4*>(&comb[p][g0+2]);   // A2,B2,A3,B3
        #pragma unroll
        for (int j = 0; j < 3; j++) {
            float2 t = tw[j];
            ae[j][0] += f0.x*t.x - f0.y*t.y;
            ae[j][1] += f0.z*t.x - f0.w*t.y;
            ae[j][2] += f1.x*t.x - f1.y*t.y;
            ae[j][3] += f1.z*t.x - f1.w*t.y;
            tw[j] = cmul(t, rr[j]);
        }
        float4 h0 = *reinterpret_cast<const float4*>(&comb[p+1][g0]);
        float4 h1 = *reinterpret_cast<const float4*>(&comb[p+1][g0+2]);
        #pragma unroll
        for (int j = 0; j < 3; j++) {
            float2 t = tw[j];
            ao[j][0] += h0.x*t.x - h0.y*t.y;
            ao[j][1] += h0.z*t.x - h0.w*t.y;
            ao[j][2] += h1.x*t.x - h1.y*t.y;
            ao[j][3] += h1.z*t.x - h1.w*t.y;
            tw[j] = cmul(t, rr[j]);
        }
    }
    {   // tail p = 34 (even)
        float4 f0 = *reinterpret_cast<const float4*>(&comb[34][g0]);
        float4 f1 = *reinterpret_cast<const float4*>(&comb[34][g0+2]);
        #pragma unroll
        for (int j = 0; j < 3; j++) {
            float2 t = tw[j];
            ae[j][0] += f0.x*t.x - f0.y*t.y;
            ae[j][1] += f0.z*t.x - f0.w*t.y;
            ae[j][2] += f1.x*t.x - f1.y*t.y;
            ae[j][3] += f1.z*t.x - f1.w*t.y;
        }
    }
    #pragma unroll
    for (int j = 0; j < 3; j++) {
        int x = tx*3 + j;
        float4 oA, oB;
        oA.x = (ae[j][0]+ao[j][0])*SCALE; oA.y = (ae[j][1]+ao[j][1])*SCALE;
        oA.z = (ae[j][2]+ao[j][2])*SCALE; oA.w = (ae[j][3]+ao[j][3])*SCALE;
        oB.x = (ae[j][0]-ao[j][0])*SCALE; oB.y = (ae[j][1]-ao[j][1])*SCALE;
        oB.z = (ae[j][2]-ao[j][2])*SCALE; oB.w = (ae[j][3]-ao[j][3])*SCALE;
        *reinterpret_cast<float4*>(&out[(((size_t)(b*HH + x)) * WW + y) * FF + g0]) = oA;
        *reinterpret_cast<float4*>(&out[(((size_t)(b*HH + x + 96)) * WW + y) * FF + g0]) = oB;
    }
}

extern "C" void kernel_launch(void* const* d_in, const int* in_sizes, int n_in,
                              void* d_out, int out_size, void* d_ws, size_t ws_size,
                              hipStream_t stream) {
    const float* in = (const float*)d_in[0];
    const float* kr = (const float*)d_in[1];
    const float* ki = (const float*)d_in[2];
    float* out = (float*)d_out;
    char* ws = (char*)d_ws;
    float2* KQ  = (float2*)(ws + OFF_KQ);
    float2* T1  = (float2*)(ws + OFF_T1);
    float2* T2  = (float2*)(ws + OFF_T2);
    float2* M2  = (float2*)(ws + OFF_M2);
    float2* M3  = (float2*)(ws + OFF_M3);

    k_front <<<dim3(NBI*NBI + 576), 256, 0, stream>>>(in, kr, ki, KQ, T1);
    k_dft_w <<<dim3(NROW, BB, 4), 256, 0, stream>>>(T1, T2);
    k_mix   <<<NBI*NBI, 256, 0, stream>>>(T2, KQ, M2);
    k_idft_w<<<dim3(NBI, BB), 384, 0, stream>>>(M2, M3);
    k_idft_h<<<dim3(HH, BB), 256, 0, stream>>>(M3, out);
}

// Round 18
// 128.790 us; speedup vs baseline: 1.3561x; 1.0038x over previous
//
#include <hip/hip_runtime.h>
#include <math.h>

#ifndef M_PI
#define M_PI 3.14159265358979323846
#endif

// Problem constants
#define HH 192
#define WW 192
#define CC 16
#define FF 32
#define BB 8
#define NBI 68        // active frequency box per spatial axis (freqs -34..33)
#define NROW 35       // computed H-spectrum rows: s = 0..34 (rest by conj symmetry)
#define NCOL 69       // computed W-spectrum cols: sj = -34..34 (col = sj+34)
#define ROW0 62       // first centered (pre-fftshift) row of the mask box
#define MASK_T 4560   // (2i-191)^2 + (2j-191)^2 <= 4560  <=>  d/dmax < 0.25 (exact)
#define NWC (WW*CC)   // 3072
#define SCALE (1.0f/1179648.0f)   // 1/(192*192*32) ifft normalization
#define NDFTH 576     // dft_h blocks in k_front — FIRST in grid (longest-job-first)

// Workspace layout (bytes). ws_size = 256 MiB; fully de-aliased.
// Peak = 71,388,160 B.
#define OFF_KQ   4096ull        // 68*68*16*32 float2 = 18,939,904 -> ends 18,944,000
#define OFF_T1   18944000ull    // 2 * 8*35*3072 float2 = 13,762,560 -> ends 32,706,560
#define OFF_T2   32706560ull    // 8*35*69*16 float2 = 2,472,960 -> ends 35,179,520
#define OFF_M2   35179520ull    // 8*68*68*32 float2 = 9,469,952 -> ends 44,649,472
#define OFF_M3   44649472ull    // 8*192*68*32 float2 = 26,738,688 -> ends 71,388,160
#define T1PART   (BB*NROW*NWC)  // float2 elems per h-quad partial (860,160)

__device__ __forceinline__ float2 cmul(float2 a, float2 b) {
    return make_float2(a.x*b.x - a.y*b.y, a.x*b.y + a.y*b.x);
}

// Build the 192-root twiddle table in LDS: tl[t] = e^{+2pi i t/192}.
// Table error ~1e-7 (sincosf) — negligible vs fp32 recurrence error.
__device__ __forceinline__ void build_twiddles(float2* tl, int tid) {
    if (tid < 192) {
        float th = (float)(2.0 * M_PI / 192.0) * (float)tid;
        float s, c;
        sincosf(th, &s, &c);
        tl[tid] = make_float2(c, s);
    }
}

// K_FRONT: blocks [0, NDFTH) do the partial forward DFT over H (radix-4,
// 4 rows x 3 wc per thread — the VGPR-64 shape); blocks [NDFTH, +68*68)
// densify the weights into KQ. Long dft_h blocks go FIRST so the short
// densify blocks backfill SIMDs while dft_h's strided loads are in flight.
__global__ __launch_bounds__(256) void k_front(
        const float* __restrict__ in, const float* __restrict__ kr,
        const float* __restrict__ ki, float2* __restrict__ KQ,
        float2* __restrict__ T1) {
    int tid = threadIdx.x;
    __shared__ float2 tl[192];
    build_twiddles(tl, tid);
    __syncthreads();

    if (blockIdx.x < NDFTH) {
        // ---- dft_h (radix-4 over h): T1(s) = sum_{h<48} v_{s mod 4}(h) e^{-2pi i s h/192}
        int idx = blockIdx.x;             // 0..575
        int b   = idx / 72;
        int rem = idx - b*72;
        int bg  = rem >> 3;               // 0..8, 4 rows each
        int zc  = rem & 7;                // quarter*2 + part
        int z   = zc >> 1;
        int part = zc & 1;
        int h0 = part * 24;
        const float* inb = in + (size_t)b * HH * NWC;
        int wc0 = z * 768 + tid;
        float2 tw[4], r[4];
        #pragma unroll
        for (int u = 0; u < 4; u++) {
            int row = bg*4 + u;
            int s = row < NROW ? row : 0;
            float2 tv = tl[s];
            r[u] = make_float2(tv.x, -tv.y);          // e^{-2pi i s/192}
            float2 t0 = tl[(s*h0) % 192];
            tw[u] = make_float2(t0.x, -t0.y);         // e^{-2pi i s h0/192}
        }
        float2 acc[4][3];
        #pragma unroll
        for (int u = 0; u < 4; u++)
            #pragma unroll
            for (int k = 0; k < 3; k++) acc[u][k] = make_float2(0.f, 0.f);
        for (int h = h0; h < h0 + 24; h++) {
            const float* p0 = inb + (size_t)h * NWC + wc0;
            const float* p1 = p0 + 48*NWC;
            const float* p2 = p0 + 96*NWC;
            const float* p3 = p0 + 144*NWC;
            float a0=p0[0], a1=p0[256], a2=p0[512];
            float e0=p1[0], e1=p1[256], e2=p1[512];
            float c0=p2[0], c1=p2[256], c2=p2[512];
            float d0=p3[0], d1=p3[256], d2=p3[512];
            float t0_0=a0+c0, t1_0=e0+d0, t2_0=a0-c0, t3_0=e0-d0;
            float t0_1=a1+c1, t1_1=e1+d1, t2_1=a1-c1, t3_1=e1-d1;
            float t0_2=a2+c2, t1_2=e2+d2, t2_2=a2-c2, t3_2=e2-d2;
            float v0_0=t0_0+t1_0, v2_0=t0_0-t1_0;
            float v0_1=t0_1+t1_1, v2_1=t0_1-t1_1;
            float v0_2=t0_2+t1_2, v2_2=t0_2-t1_2;
            // u=0: v0 real
            acc[0][0].x += v0_0*tw[0].x; acc[0][0].y += v0_0*tw[0].y;
            acc[0][1].x += v0_1*tw[0].x; acc[0][1].y += v0_1*tw[0].y;
            acc[0][2].x += v0_2*tw[0].x; acc[0][2].y += v0_2*tw[0].y;
            tw[0] = cmul(tw[0], r[0]);
            // u=1: v1 = (t2, -t3)
            acc[1][0].x += t2_0*tw[1].x + t3_0*tw[1].y; acc[1][0].y += t2_0*tw[1].y - t3_0*tw[1].x;
            acc[1][1].x += t2_1*tw[1].x + t3_1*tw[1].y; acc[1][1].y += t2_1*tw[1].y - t3_1*tw[1].x;
            acc[1][2].x += t2_2*tw[1].x + t3_2*tw[1].y; acc[1][2].y += t2_2*tw[1].y - t3_2*tw[1].x;
            tw[1] = cmul(tw[1], r[1]);
            // u=2: v2 real
            acc[2][0].x += v2_0*tw[2].x; acc[2][0].y += v2_0*tw[2].y;
            acc[2][1].x += v2_1*tw[2].x; acc[2][1].y += v2_1*tw[2].y;
            acc[2][2].x += v2_2*tw[2].x; acc[2][2].y += v2_2*tw[2].y;
            tw[2] = cmul(tw[2], r[2]);
            // u=3: v3 = (t2, t3)
            acc[3][0].x += t2_0*tw[3].x - t3_0*tw[3].y; acc[3][0].y += t2_0*tw[3].y + t3_0*tw[3].x;
            acc[3][1].x += t2_1*tw[3].x - t3_1*tw[3].y; acc[3][1].y += t2_1*tw[3].y + t3_1*tw[3].x;
            acc[3][2].x += t2_2*tw[3].x - t3_2*tw[3].y; acc[3][2].y += t2_2*tw[3].y + t3_2*tw[3].x;
            tw[3] = cmul(tw[3], r[3]);
        }
        #pragma unroll
        for (int u = 0; u < 4; u++) {
            int row = bg*4 + u;
            if (row < NROW) {
                float2* o = T1 + (size_t)part * T1PART + ((size_t)(b*NROW + row)) * NWC + wc0;
                o[0] = acc[u][0]; o[256] = acc[u][1]; o[512] = acc[u][2];
            }
        }
    } else {
        // ---- densify: KQ[c,g] = sum_{sc,f} e^{-2pi i c sc/16} K[sc,f] e^{+2pi i f g/32}
        int blk = blockIdx.x - NDFTH;         // bi*68 + bj
        int bi = blk / NBI, bj = blk - bi*NBI;
        float2* KQo = KQ + (size_t)blk * (CC*FF);
        int a = 2*(ROW0+bi) - 191;
        int bc = 2*(ROW0+bj) - 191;
        bool masked = (a*a + bc*bc) <= MASK_T;   // block-uniform
        if (!masked) {
            for (int e = tid; e < CC*FF; e += 256) KQo[e] = make_float2(0.f, 0.f);
            return;
        }
        __shared__ float2 Kc[CC][FF+1];
        __shared__ float2 Kt[CC][FF+1];
        __shared__ int cnts[NBI];
        __shared__ int rank_s;
        if (tid < NBI) {        // per-row masked-count (exact integer sqrt)
            int ii = ROW0 + tid;
            int aa = 2*ii - 191;
            int rem = MASK_T - aa*aa;
            int q = (int)sqrtf((float)rem);
            while ((q+1)*(q+1) <= rem) q++;
            while (q > 0 && q*q > rem) q--;
            cnts[tid] = ((191 + q) >> 1) - ((192 - q) >> 1) + 1;
        }
        __syncthreads();
        if (tid == 0) {         // rank = prefix(cnts)[bi] + (ROW0+bj) - jmin[bi]
            int acc = 0;
            for (int i = 0; i < bi; i++) acc += cnts[i];
            int ii = ROW0 + bi;
            int aa = 2*ii - 191;
            int rem = MASK_T - aa*aa;
            int q = (int)sqrtf((float)rem);
            while ((q+1)*(q+1) <= rem) q++;
            while (q > 0 && q*q > rem) q--;
            rank_s = acc + (ROW0 + bj) - ((192 - q) >> 1);
        }
        __syncthreads();
        size_t base = (size_t)rank_s * (CC*FF);
        for (int e = tid; e < CC*FF; e += 256)
            Kc[e>>5][e&31] = make_float2(kr[base+e], ki[base+e]);
        __syncthreads();
        for (int e = tid; e < CC*FF; e += 256) {      // Kt[cp][f] = DFT16_c
            int cp = e >> 5, f = e & 31;
            float2 acc = make_float2(0.f, 0.f);
            #pragma unroll
            for (int c = 0; c < CC; c++) {
                int tt = (12*c*cp) % 192;             // 2pi/16 = 2pi*12/192
                float2 w = tl[tt];
                float2 v = Kc[c][f];
                acc.x += v.x*w.x + v.y*w.y;           // v * conj(w)
                acc.y += v.y*w.x - v.x*w.y;
            }
            Kt[cp][f] = acc;
        }
        __syncthreads();
        for (int e = tid; e < CC*FF; e += 256) {      // KQ[cp][g] = iDFT32_f
            int cp = e >> 5, g = e & 31;
            float2 acc = make_float2(0.f, 0.f);
            #pragma unroll
            for (int f = 0; f < FF; f++) {
                int tt = (6*f*g) % 192;               // 2pi/32 = 2pi*6/192
                float2 w = tl[tt];
                float2 v = Kt[cp][f];
                acc.x += v.x*w.x - v.y*w.y;           // v * w
                acc.y += v.x*w.y + v.y*w.x;
            }
            KQo[cp*FF + g] = acc;
        }
    }
}

// K_B: partial forward DFT over W, radix-2 over w:
// T2(col) = sum_{w=0}^{95} (S[w] +- S[w+96]) e^{-2pi i sj w/192}, class by parity(sj).
// Column dim split 4-ways across blockIdx.z for occupancy.
__global__ __launch_bounds__(256) void k_dft_w(
        const float2* __restrict__ T1, float2* __restrict__ T2) {
    int row = blockIdx.x;             // 0..34
    int b   = blockIdx.y;
    int q   = blockIdx.z;             // col quarter: bases 0,17,35,52
    const int qbase[4] = {0, 17, 35, 52};
    const int qcnt[4]  = {17, 18, 17, 17};
    int base = qbase[q], cnt = qcnt[q];
    int tid = threadIdx.x;
    __shared__ float2 tl[192];
    __shared__ float2 shp[96][CC];    // 12 KB  (S[w] + S[w+96])
    __shared__ float2 shm[96][CC];    // 12 KB  (S[w] - S[w+96])
    build_twiddles(tl, tid);
    const float2* src = T1 + ((size_t)(b*NROW + row)) * NWC;
    for (int e = tid; e < 96*CC; e += 256) {
        float2 a0 = src[e];
        float2 a1 = src[e + T1PART];
        float2 b0 = src[e + 96*CC];
        float2 b1 = src[e + 96*CC + T1PART];
        float Sx = a0.x + a1.x, Sy = a0.y + a1.y;
        float Tx = b0.x + b1.x, Ty = b0.y + b1.y;
        shp[e>>4][e&15] = make_float2(Sx + Tx, Sy + Ty);
        shm[e>>4][e&15] = make_float2(Sx - Tx, Sy - Ty);
    }
    __syncthreads();
    int c = tid >> 4;                 // 0..15
    int bjL = tid & 15;               // 0..15
    // parity(col) = (base + bjL + 16k)&1 = (base + bjL)&1 (constant over k)
    const float2* shsel = ((base + bjL) & 1) ? &shm[0][0] : &shp[0][0];
    float2 tw[2], r[2], acc[2];
    #pragma unroll
    for (int k = 0; k < 2; k++) {
        int off = bjL + 16*k;
        int col = base + off;
        bool valid = off < cnt;
        int sj = (valid ? col : 34) - 34;
        tw[k] = make_float2(1.f, 0.f);
        acc[k] = make_float2(0.f, 0.f);
        int ts = ((sj % 192) + 192) % 192;
        float2 tv = tl[ts];
        r[k] = make_float2(tv.x, -tv.y);
    }
    for (int w = 0; w < 96; w++) {
        float2 av = shsel[w*CC + c];
        #pragma unroll
        for (int k = 0; k < 2; k++) {
            acc[k].x += av.x*tw[k].x - av.y*tw[k].y;
            acc[k].y += av.x*tw[k].y + av.y*tw[k].x;
            tw[k] = cmul(tw[k], r[k]);
        }
    }
    float2* dst = T2 + ((size_t)((b*NROW + row)*NCOL)) * CC;
    #pragma unroll
    for (int k = 0; k < 2; k++) {
        int off = bjL + 16*k;
        int col = base + off;
        if (off < cnt) dst[col*CC + c] = acc[k];
    }
}

// K_M: per-site 16->32 complex matvec; negative-s rows read the conj mirror.
__global__ __launch_bounds__(256) void k_mix(
        const float2* __restrict__ T2, const float2* __restrict__ KQ,
        float2* __restrict__ M2) {
    int site = blockIdx.x;            // bi*68 + bj
    int bi = site / NBI, bj = site - bi*NBI;
    int tid = threadIdx.x;
    int b = tid >> 5;                 // 8 groups of 32 lanes
    int g = tid & 31;
    int row, col;
    bool cj;
    if (bi >= 34) { row = bi - 34; col = bj;      cj = false; }
    else          { row = 34 - bi; col = 68 - bj; cj = true;  }
    const float2* x  = T2 + ((size_t)(b*NROW + row) * NCOL + col) * CC;
    const float2* kq = KQ + (size_t)site * (CC*FF);
    float sgn = cj ? -1.f : 1.f;
    float2 acc = make_float2(0.f, 0.f);
    #pragma unroll
    for (int cp = 0; cp < CC; cp++) {
        float2 xv = x[cp];
        xv.y *= sgn;
        float2 kv = kq[cp*FF + g];
        acc.x += xv.x*kv.x - xv.y*kv.y;
        acc.y += xv.x*kv.y + xv.y*kv.x;
    }
    M2[((size_t)b * (NBI*NBI) + site) * FF + g] = acc;
}

// K_E2: inverse DFT over W — LDS-broadcast + RADIX-4 over y, single-stage.
// One 384-thread block per (bi,b): stages the [68][32] M2 slice once.
// Thread = (ty 0..47, gq 0..7): y = ty, 4 g; radix-4 classes give
// y, y+48, y+96, y+144.  M3 layout [b][y][bi][g].
__global__ __launch_bounds__(384) void k_idft_w(
        const float2* __restrict__ M2, float2* __restrict__ M3) {
    int bi = blockIdx.x;
    int b  = blockIdx.y;
    int tid = threadIdx.x;
    int gq = tid & 7;                    // 0..7
    int ty = tid >> 3;                   // 0..47
    int g0 = gq * 4;
    int y  = ty;                         // [0,48)
    __shared__ float2 tl[192];
    __shared__ __align__(16) float2 m2s[NBI][FF];   // 17.4 KB
    build_twiddles(tl, tid);
    {
        const float4* src = reinterpret_cast<const float4*>(
            M2 + ((size_t)b*(NBI*NBI) + (size_t)bi*NBI) * FF);
        float4* dst = reinterpret_cast<float4*>(&m2s[0][0]);
        for (int e = tid; e < NBI*FF/2; e += 384) dst[e] = src[e];
    }
    __syncthreads();
    float2 tw = tl[(158*y) % 192];       // e^{+2pi i (-34) y/192}
    float2 rr = tl[y];                   // e^{+2pi i y/192}
    float2 zz = make_float2(0.f, 0.f);
    float2 C0[4] = {zz,zz,zz,zz};        // class 0: bj-34 ≡ 0 (mod 4)
    float2 C1[4] = {zz,zz,zz,zz};
    float2 C2[4] = {zz,zz,zz,zz};
    float2 C3[4] = {zz,zz,zz,zz};
#define IW_STEP(ROW, CL) { \
    float4 e0 = *reinterpret_cast<const float4*>(&m2s[ROW][g0]); \
    float4 e1 = *reinterpret_cast<const float4*>(&m2s[ROW][g0+2]); \
    CL[0].x += e0.x*tw.x - e0.y*tw.y;  CL[0].y += e0.x*tw.y + e0.y*tw.x; \
    CL[1].x += e0.z*tw.x - e0.w*tw.y;  CL[1].y += e0.z*tw.y + e0.w*tw.x; \
    CL[2].x += e1.x*tw.x - e1.y*tw.y;  CL[2].y += e1.x*tw.y + e1.y*tw.x; \
    CL[3].x += e1.z*tw.x - e1.w*tw.y;  CL[3].y += e1.z*tw.y + e1.w*tw.x; \
    tw = cmul(tw, rr); }
    for (int bj = 0; bj < NBI; bj += 4) {
        // bj-34 mod 4: bj+0 -> 2, bj+1 -> 3, bj+2 -> 0, bj+3 -> 1
        IW_STEP(bj,   C2)
        IW_STEP(bj+1, C3)
        IW_STEP(bj+2, C0)
        IW_STEP(bj+3, C1)
    }
#undef IW_STEP
    // Combine: out(y+48k) = sum_m i^{mk} C_m
    float2 R0[4], R1[4], R2[4], R3[4];
    #pragma unroll
    for (int k = 0; k < 4; k++) {
        float2 p = make_float2(C0[k].x + C2[k].x, C0[k].y + C2[k].y);
        float2 q = make_float2(C1[k].x + C3[k].x, C1[k].y + C3[k].y);
        float2 m = make_float2(C0[k].x - C2[k].x, C0[k].y - C2[k].y);
        float2 n = make_float2(C1[k].x - C3[k].x, C1[k].y - C3[k].y);
        R0[k] = make_float2(p.x + q.x, p.y + q.y);        // y
        R2[k] = make_float2(p.x - q.x, p.y - q.y);        // y+96
        R1[k] = make_float2(m.x - n.y, m.y + n.x);        // y+48  (m + i n)
        R3[k] = make_float2(m.x + n.y, m.y - n.x);        // y+144 (m - i n)
    }
    // M3[b][y][bi][g]
    float2* p0 = M3 + (((size_t)b*HH + y)*NBI + bi)*FF + g0;
    *reinterpret_cast<float4*>(p0)     = make_float4(R0[0].x,R0[0].y,R0[1].x,R0[1].y);
    *reinterpret_cast<float4*>(p0 + 2) = make_float4(R0[2].x,R0[2].y,R0[3].x,R0[3].y);
    float2* p1 = M3 + (((size_t)b*HH + y + 48)*NBI + bi)*FF + g0;
    *reinterpret_cast<float4*>(p1)     = make_float4(R1[0].x,R1[0].y,R1[1].x,R1[1].y);
    *reinterpret_cast<float4*>(p1 + 2) = make_float4(R1[2].x,R1[2].y,R1[3].x,R1[3].y);
    float2* p2 = M3 + (((size_t)b*HH + y + 96)*NBI + bi)*FF + g0;
    *reinterpret_cast<float4*>(p2)     = make_float4(R2[0].x,R2[0].y,R2[1].x,R2[1].y);
    *reinterpret_cast<float4*>(p2 + 2) = make_float4(R2[2].x,R2[2].y,R2[3].x,R2[3].y);
    float2* p3 = M3 + (((size_t)b*HH + y + 144)*NBI + bi)*FF + g0;
    *reinterpret_cast<float4*>(p3)     = make_float4(R3[0].x,R3[0].y,R3[1].x,R3[1].y);
    *reinterpret_cast<float4*>(p3 + 2) = make_float4(R3[2].x,R3[2].y,R3[3].x,R3[3].y);
}

// K_E3: inverse DFT over H keeping Re only, Hermitian (s,-s) pairing AND
// radix-2 over x: even/odd-p accumulators give out(x) = E+O, out(x+96) = E-O.
// comb[p][g] = (A,B):  contribution = A*cos(2pi p x/192) - B*sin(...).
// M3 layout [b][y][bi][g]: this block's slice is one contiguous 17.4 KB read.
__global__ __launch_bounds__(256) void k_idft_h(
        const float2* __restrict__ M3, float* __restrict__ out) {
    int y = blockIdx.x;
    int b = blockIdx.y;
    int tid = threadIdx.x;
    const float2* m3s = M3 + ((size_t)b*HH + y)*NBI*FF;   // [bi][g] slice
    __shared__ float2 tl[192];
    __shared__ __align__(16) float2 comb[NROW][FF];   // (A,B) per pair, 8.96 KB
    build_twiddles(tl, tid);
    for (int e = tid; e < NROW*FF; e += 256) {
        int p = e >> 5, g = e & 31;
        float A, Bv;
        if (p == 0) {
            float2 v = m3s[34*FF + g];
            A = v.x; Bv = 0.f;
        } else if (p == 34) {
            float2 v = m3s[0*FF + g];
            A = v.x; Bv = -v.y;
        } else {
            float2 vp = m3s[(34 + p)*FF + g];
            float2 vm = m3s[(34 - p)*FF + g];
            A = vp.x + vm.x; Bv = vp.y - vm.y;
        }
        comb[p][g] = make_float2(A, Bv);
    }
    __syncthreads();
    int tx = tid >> 3;          // 0..31  (3 x-pairs per thread: x = tx*3+j)
    int tg = tid & 7;
    int g0 = tg * 4;
    float2 tw[3], rr[3];
    float ae[3][4], ao[3][4];
    #pragma unroll
    for (int j = 0; j < 3; j++) {
        int x = tx*3 + j;
        tw[j] = make_float2(1.f, 0.f);   // angle p=0
        rr[j] = tl[x];                   // e^{+2pi i x/192} per p step
        #pragma unroll
        for (int q = 0; q < 4; q++) { ae[j][q] = 0.f; ao[j][q] = 0.f; }
    }
    for (int p = 0; p < 34; p += 2) {
        float4 f0 = *reinterpret_cast<const float4*>(&comb[p][g0]);     // A0,B0,A1,B1
        float4 f1 = *reinterpret_cast<const float4*>(&comb[p][g0+2]);   // A2,B2,A3,B3
        #pragma unroll
        for (int j = 0; j < 3; j++) {
            float2 t = tw[j];
            ae[j][0] += f0.x*t.x - f0.y*t.y;
            ae[j][1] += f0.z*t.x - f0.w*t.y;
            ae[j][2] += f1.x*t.x - f1.y*t.y;
            ae[j][3] += f1.z*t.x - f1.w*t.y;
            tw[j] = cmul(t, rr[j]);
        }
        float4 h0 = *reinterpret_cast<const float4*>(&comb[p+1][g0]);
        float4 h1 = *reinterpret_cast<const float4*>(&comb[p+1][g0+2]);
        #pragma unroll
        for (int j = 0; j < 3; j++) {
            float2 t = tw[j];
            ao[j][0] += h0.x*t.x - h0.y*t.y;
            ao[j][1] += h0.z*t.x - h0.w*t.y;
            ao[j][2] += h1.x*t.x - h1.y*t.y;
            ao[j][3] += h1.z*t.x - h1.w*t.y;
            tw[j] = cmul(t, rr[j]);
        }
    }
    {   // tail p = 34 (even)
        float4 f0 = *reinterpret_cast<const float4*>(&comb[34][g0]);
        float4 f1 = *reinterpret_cast<const float4*>(&comb[34][g0+2]);
        #pragma unroll
        for (int j = 0; j < 3; j++) {
            float2 t = tw[j];
            ae[j][0] += f0.x*t.x - f0.y*t.y;
            ae[j][1] += f0.z*t.x - f0.w*t.y;
            ae[j][2] += f1.x*t.x - f1.y*t.y;
            ae[j][3] += f1.z*t.x - f1.w*t.y;
        }
    }
    #pragma unroll
    for (int j = 0; j < 3; j++) {
        int x = tx*3 + j;
        float4 oA, oB;
        oA.x = (ae[j][0]+ao[j][0])*SCALE; oA.y = (ae[j][1]+ao[j][1])*SCALE;
        oA.z = (ae[j][2]+ao[j][2])*SCALE; oA.w = (ae[j][3]+ao[j][3])*SCALE;
        oB.x = (ae[j][0]-ao[j][0])*SCALE; oB.y = (ae[j][1]-ao[j][1])*SCALE;
        oB.z = (ae[j][2]-ao[j][2])*SCALE; oB.w = (ae[j][3]-ao[j][3])*SCALE;
        *reinterpret_cast<float4*>(&out[(((size_t)(b*HH + x)) * WW + y) * FF + g0]) = oA;
        *reinterpret_cast<float4*>(&out[(((size_t)(b*HH + x + 96)) * WW + y) * FF + g0]) = oB;
    }
}

extern "C" void kernel_launch(void* const* d_in, const int* in_sizes, int n_in,
                              void* d_out, int out_size, void* d_ws, size_t ws_size,
                              hipStream_t stream) {
    const float* in = (const float*)d_in[0];
    const float* kr = (const float*)d_in[1];
    const float* ki = (const float*)d_in[2];
    float* out = (float*)d_out;
    char* ws = (char*)d_ws;
    float2* KQ  = (float2*)(ws + OFF_KQ);
    float2* T1  = (float2*)(ws + OFF_T1);
    float2* T2  = (float2*)(ws + OFF_T2);
    float2* M2  = (float2*)(ws + OFF_M2);
    float2* M3  = (float2*)(ws + OFF_M3);

    k_front <<<dim3(NDFTH + NBI*NBI), 256, 0, stream>>>(in, kr, ki, KQ, T1);
    k_dft_w <<<dim3(NROW, BB, 4), 256, 0, stream>>>(T1, T2);
    k_mix   <<<NBI*NBI, 256, 0, stream>>>(T2, KQ, M2);
    k_idft_w<<<dim3(NBI, BB), 384, 0, stream>>>(M2, M3);
    k_idft_h<<<dim3(HH, BB), 256, 0, stream>>>(M3, out);
}

// Round 19
// 111.231 us; speedup vs baseline: 1.5701x; 1.1579x over previous
//
#include <hip/hip_runtime.h>
#include <math.h>

#ifndef M_PI
#define M_PI 3.14159265358979323846
#endif

// Problem constants
#define HH 192
#define WW 192
#define CC 16
#define FF 32
#define BB 8
#define NBI 68        // active frequency box per spatial axis (freqs -34..33)
#define NROW 35       // computed H-spectrum rows: s = 0..34 (rest by conj symmetry)
#define NCOL 69       // computed W-spectrum cols: sj = -34..34 (col = sj+34)
#define ROW0 62       // first centered (pre-fftshift) row of the mask box
#define MASK_T 4560   // (2i-191)^2 + (2j-191)^2 <= 4560  <=>  d/dmax < 0.25 (exact)
#define NWC (WW*CC)   // 3072
#define SCALE (1.0f/1179648.0f)   // 1/(192*192*32) ifft normalization
#define NDFTH 576     // dft_h blocks in k_front — FIRST in grid (longest-job-first)

// Workspace layout (bytes). ws_size = 256 MiB; fully de-aliased.
// Peak = 71,388,160 B.
#define OFF_KQ   4096ull        // 68*68*16*32 float2 = 18,939,904 -> ends 18,944,000
#define OFF_T1   18944000ull    // 2 * 8*35*3072 float2 = 13,762,560 -> ends 32,706,560
#define OFF_T2   32706560ull    // 8*35*69*16 float2 = 2,472,960 -> ends 35,179,520
#define OFF_M2   35179520ull    // 8*68*68*32 float2 = 9,469,952 -> ends 44,649,472
#define OFF_M3   44649472ull    // 8*192*68*32 float2 = 26,738,688 -> ends 71,388,160
#define T1PART   (BB*NROW*NWC)  // float2 elems per h-quad partial (860,160)

__device__ __forceinline__ float2 cmul(float2 a, float2 b) {
    return make_float2(a.x*b.x - a.y*b.y, a.x*b.y + a.y*b.x);
}

// Build the 192-root twiddle table in LDS: tl[t] = e^{+2pi i t/192}.
// Table error ~1e-7 (sincosf) — negligible vs fp32 recurrence error.
__device__ __forceinline__ void build_twiddles(float2* tl, int tid) {
    if (tid < 192) {
        float th = (float)(2.0 * M_PI / 192.0) * (float)tid;
        float s, c;
        sincosf(th, &s, &c);
        tl[tid] = make_float2(c, s);
    }
}

// K_FRONT: blocks [0, NDFTH) do the partial forward DFT over H (radix-4,
// 4 rows x 3 wc per thread — the VGPR-64 shape); blocks [NDFTH, +68*68)
// densify the weights into KQ with RADIX-4 DFT16/iDFT32 (inner loops 4 and 8
// instead of 16 and 32 — exact butterfly precombines in LDS).
__global__ __launch_bounds__(256) void k_front(
        const float* __restrict__ in, const float* __restrict__ kr,
        const float* __restrict__ ki, float2* __restrict__ KQ,
        float2* __restrict__ T1) {
    int tid = threadIdx.x;
    __shared__ float2 tl[192];
    build_twiddles(tl, tid);
    __syncthreads();

    if (blockIdx.x < NDFTH) {
        // ---- dft_h (radix-4 over h): T1(s) = sum_{h<48} v_{s mod 4}(h) e^{-2pi i s h/192}
        int idx = blockIdx.x;             // 0..575
        int b   = idx / 72;
        int rem = idx - b*72;
        int bg  = rem >> 3;               // 0..8, 4 rows each
        int zc  = rem & 7;                // quarter*2 + part
        int z   = zc >> 1;
        int part = zc & 1;
        int h0 = part * 24;
        const float* inb = in + (size_t)b * HH * NWC;
        int wc0 = z * 768 + tid;
        float2 tw[4], r[4];
        #pragma unroll
        for (int u = 0; u < 4; u++) {
            int row = bg*4 + u;
            int s = row < NROW ? row : 0;
            float2 tv = tl[s];
            r[u] = make_float2(tv.x, -tv.y);          // e^{-2pi i s/192}
            float2 t0 = tl[(s*h0) % 192];
            tw[u] = make_float2(t0.x, -t0.y);         // e^{-2pi i s h0/192}
        }
        float2 acc[4][3];
        #pragma unroll
        for (int u = 0; u < 4; u++)
            #pragma unroll
            for (int k = 0; k < 3; k++) acc[u][k] = make_float2(0.f, 0.f);
        for (int h = h0; h < h0 + 24; h++) {
            const float* p0 = inb + (size_t)h * NWC + wc0;
            const float* p1 = p0 + 48*NWC;
            const float* p2 = p0 + 96*NWC;
            const float* p3 = p0 + 144*NWC;
            float a0=p0[0], a1=p0[256], a2=p0[512];
            float e0=p1[0], e1=p1[256], e2=p1[512];
            float c0=p2[0], c1=p2[256], c2=p2[512];
            float d0=p3[0], d1=p3[256], d2=p3[512];
            float t0_0=a0+c0, t1_0=e0+d0, t2_0=a0-c0, t3_0=e0-d0;
            float t0_1=a1+c1, t1_1=e1+d1, t2_1=a1-c1, t3_1=e1-d1;
            float t0_2=a2+c2, t1_2=e2+d2, t2_2=a2-c2, t3_2=e2-d2;
            float v0_0=t0_0+t1_0, v2_0=t0_0-t1_0;
            float v0_1=t0_1+t1_1, v2_1=t0_1-t1_1;
            float v0_2=t0_2+t1_2, v2_2=t0_2-t1_2;
            // u=0: v0 real
            acc[0][0].x += v0_0*tw[0].x; acc[0][0].y += v0_0*tw[0].y;
            acc[0][1].x += v0_1*tw[0].x; acc[0][1].y += v0_1*tw[0].y;
            acc[0][2].x += v0_2*tw[0].x; acc[0][2].y += v0_2*tw[0].y;
            tw[0] = cmul(tw[0], r[0]);
            // u=1: v1 = (t2, -t3)
            acc[1][0].x += t2_0*tw[1].x + t3_0*tw[1].y; acc[1][0].y += t2_0*tw[1].y - t3_0*tw[1].x;
            acc[1][1].x += t2_1*tw[1].x + t3_1*tw[1].y; acc[1][1].y += t2_1*tw[1].y - t3_1*tw[1].x;
            acc[1][2].x += t2_2*tw[1].x + t3_2*tw[1].y; acc[1][2].y += t2_2*tw[1].y - t3_2*tw[1].x;
            tw[1] = cmul(tw[1], r[1]);
            // u=2: v2 real
            acc[2][0].x += v2_0*tw[2].x; acc[2][0].y += v2_0*tw[2].y;
            acc[2][1].x += v2_1*tw[2].x; acc[2][1].y += v2_1*tw[2].y;
            acc[2][2].x += v2_2*tw[2].x; acc[2][2].y += v2_2*tw[2].y;
            tw[2] = cmul(tw[2], r[2]);
            // u=3: v3 = (t2, t3)
            acc[3][0].x += t2_0*tw[3].x - t3_0*tw[3].y; acc[3][0].y += t2_0*tw[3].y + t3_0*tw[3].x;
            acc[3][1].x += t2_1*tw[3].x - t3_1*tw[3].y; acc[3][1].y += t2_1*tw[3].y + t3_1*tw[3].x;
            acc[3][2].x += t2_2*tw[3].x - t3_2*tw[3].y; acc[3][2].y += t2_2*tw[3].y + t3_2*tw[3].x;
            tw[3] = cmul(tw[3], r[3]);
        }
        #pragma unroll
        for (int u = 0; u < 4; u++) {
            int row = bg*4 + u;
            if (row < NROW) {
                float2* o = T1 + (size_t)part * T1PART + ((size_t)(b*NROW + row)) * NWC + wc0;
                o[0] = acc[u][0]; o[256] = acc[u][1]; o[512] = acc[u][2];
            }
        }
    } else {
        // ---- densify (radix-4 on both small DFTs):
        // Kt[cp][f] = sum_{c0<4} VA[cp&3][c0][f] * conj(tl[12 c0 cp])
        //   with VA[m][c0][f] = sum_k (-i)^{km} Kc[c0+4k][f]
        // KQ[cp][g] = sum_{f0<8} WB[cp][f0][g&3] * tl[6 f0 g]
        //   with WB[cp][f0][m] = sum_k i^{km} Kt[cp][f0+8k]
        int blk = blockIdx.x - NDFTH;         // bi*68 + bj
        int bi = blk / NBI, bj = blk - bi*NBI;
        float2* KQo = KQ + (size_t)blk * (CC*FF);
        int a = 2*(ROW0+bi) - 191;
        int bc = 2*(ROW0+bj) - 191;
        bool masked = (a*a + bc*bc) <= MASK_T;   // block-uniform
        if (!masked) {
            for (int e = tid; e < CC*FF; e += 256) KQo[e] = make_float2(0.f, 0.f);
            return;
        }
        __shared__ float2 Kc[CC][FF+1];
        __shared__ float2 VA[4][4][FF];     // [m][c0][f]  (m wave-uniform on read)
        __shared__ float2 Kt[CC][FF+1];
        __shared__ float2 WB[CC][8][4];     // [cp][f0][m] (m innermost: quad-adjacent)
        __shared__ int cnts[NBI];
        __shared__ int rank_s;
        if (tid < NBI) {        // per-row masked-count (exact integer sqrt)
            int ii = ROW0 + tid;
            int aa = 2*ii - 191;
            int rem = MASK_T - aa*aa;
            int q = (int)sqrtf((float)rem);
            while ((q+1)*(q+1) <= rem) q++;
            while (q > 0 && q*q > rem) q--;
            cnts[tid] = ((191 + q) >> 1) - ((192 - q) >> 1) + 1;
        }
        __syncthreads();
        if (tid == 0) {         // rank = prefix(cnts)[bi] + (ROW0+bj) - jmin[bi]
            int acc = 0;
            for (int i = 0; i < bi; i++) acc += cnts[i];
            int ii = ROW0 + bi;
            int aa = 2*ii - 191;
            int rem = MASK_T - aa*aa;
            int q = (int)sqrtf((float)rem);
            while ((q+1)*(q+1) <= rem) q++;
            while (q > 0 && q*q > rem) q--;
            rank_s = acc + (ROW0 + bj) - ((192 - q) >> 1);
        }
        __syncthreads();
        size_t base = (size_t)rank_s * (CC*FF);
        for (int e = tid; e < CC*FF; e += 256)
            Kc[e>>5][e&31] = make_float2(kr[base+e], ki[base+e]);
        __syncthreads();
        if (tid < 128) {        // fill A: radix-4 precombine over c
            int c0 = tid >> 5, f = tid & 31;
            float2 K0 = Kc[c0][f], K1 = Kc[c0+4][f], K2 = Kc[c0+8][f], K3 = Kc[c0+12][f];
            float Px = K0.x+K2.x, Py = K0.y+K2.y;
            float Mx = K0.x-K2.x, My = K0.y-K2.y;
            float Qx = K1.x+K3.x, Qy = K1.y+K3.y;
            float Nx = K1.x-K3.x, Ny = K1.y-K3.y;
            VA[0][c0][f] = make_float2(Px+Qx, Py+Qy);
            VA[2][c0][f] = make_float2(Px-Qx, Py-Qy);
            VA[1][c0][f] = make_float2(Mx+Ny, My-Nx);   // M - iN
            VA[3][c0][f] = make_float2(Mx-Ny, My+Nx);   // M + iN
        }
        __syncthreads();
        #pragma unroll
        for (int rep = 0; rep < 2; rep++) {     // Kt: 4-tap inner loop
            int idx = tid + rep*256;
            int cp = idx >> 5, f = idx & 31;
            int m = cp & 3;
            float2 acc = make_float2(0.f, 0.f);
            #pragma unroll
            for (int c0 = 0; c0 < 4; c0++) {
                float2 w = tl[(12*c0*cp) % 192];
                float2 v = VA[m][c0][f];
                acc.x += v.x*w.x + v.y*w.y;     // v * conj(w)
                acc.y += v.y*w.x - v.x*w.y;
            }
            Kt[cp][f] = acc;
        }
        __syncthreads();
        if (tid < 128) {        // fill B: radix-4 precombine over f
            int cp = tid >> 3, f0 = tid & 7;
            float2 T0 = Kt[cp][f0], T1v = Kt[cp][f0+8], T2 = Kt[cp][f0+16], T3 = Kt[cp][f0+24];
            float Px = T0.x+T2.x, Py = T0.y+T2.y;
            float Mx = T0.x-T2.x, My = T0.y-T2.y;
            float Qx = T1v.x+T3.x, Qy = T1v.y+T3.y;
            float Nx = T1v.x-T3.x, Ny = T1v.y-T3.y;
            WB[cp][f0][0] = make_float2(Px+Qx, Py+Qy);
            WB[cp][f0][2] = make_float2(Px-Qx, Py-Qy);
            WB[cp][f0][1] = make_float2(Mx-Ny, My+Nx);   // M + iN
            WB[cp][f0][3] = make_float2(Mx+Ny, My-Nx);   // M - iN
        }
        __syncthreads();
        #pragma unroll
        for (int rep = 0; rep < 2; rep++) {     // KQ: 8-tap inner loop
            int idx = tid + rep*256;
            int cp = idx >> 5, g = idx & 31;
            int m = g & 3;
            float2 acc = make_float2(0.f, 0.f);
            #pragma unroll
            for (int f0 = 0; f0 < 8; f0++) {
                float2 w = tl[(6*f0*g) % 192];
                float2 v = WB[cp][f0][m];
                acc.x += v.x*w.x - v.y*w.y;     // v * w
                acc.y += v.x*w.y + v.y*w.x;
            }
            KQo[cp*FF + g] = acc;
        }
    }
}

// K_B: partial forward DFT over W, radix-2 over w:
// T2(col) = sum_{w=0}^{95} (S[w] +- S[w+96]) e^{-2pi i sj w/192}, class by parity(sj).
// Column dim split 4-ways across blockIdx.z for occupancy.
__global__ __launch_bounds__(256) void k_dft_w(
        const float2* __restrict__ T1, float2* __restrict__ T2) {
    int row = blockIdx.x;             // 0..34
    int b   = blockIdx.y;
    int q   = blockIdx.z;             // col quarter: bases 0,17,35,52
    const int qbase[4] = {0, 17, 35, 52};
    const int qcnt[4]  = {17, 18, 17, 17};
    int base = qbase[q], cnt = qcnt[q];
    int tid = threadIdx.x;
    __shared__ float2 tl[192];
    __shared__ float2 shp[96][CC];    // 12 KB  (S[w] + S[w+96])
    __shared__ float2 shm[96][CC];    // 12 KB  (S[w] - S[w+96])
    build_twiddles(tl, tid);
    const float2* src = T1 + ((size_t)(b*NROW + row)) * NWC;
    for (int e = tid; e < 96*CC; e += 256) {
        float2 a0 = src[e];
        float2 a1 = src[e + T1PART];
        float2 b0 = src[e + 96*CC];
        float2 b1 = src[e + 96*CC + T1PART];
        float Sx = a0.x + a1.x, Sy = a0.y + a1.y;
        float Tx = b0.x + b1.x, Ty = b0.y + b1.y;
        shp[e>>4][e&15] = make_float2(Sx + Tx, Sy + Ty);
        shm[e>>4][e&15] = make_float2(Sx - Tx, Sy - Ty);
    }
    __syncthreads();
    int c = tid >> 4;                 // 0..15
    int bjL = tid & 15;               // 0..15
    // parity(col) = (base + bjL + 16k)&1 = (base + bjL)&1 (constant over k)
    const float2* shsel = ((base + bjL) & 1) ? &shm[0][0] : &shp[0][0];
    float2 tw[2], r[2], acc[2];
    #pragma unroll
    for (int k = 0; k < 2; k++) {
        int off = bjL + 16*k;
        int col = base + off;
        bool valid = off < cnt;
        int sj = (valid ? col : 34) - 34;
        tw[k] = make_float2(1.f, 0.f);
        acc[k] = make_float2(0.f, 0.f);
        int ts = ((sj % 192) + 192) % 192;
        float2 tv = tl[ts];
        r[k] = make_float2(tv.x, -tv.y);
    }
    for (int w = 0; w < 96; w++) {
        float2 av = shsel[w*CC + c];
        #pragma unroll
        for (int k = 0; k < 2; k++) {
            acc[k].x += av.x*tw[k].x - av.y*tw[k].y;
            acc[k].y += av.x*tw[k].y + av.y*tw[k].x;
            tw[k] = cmul(tw[k], r[k]);
        }
    }
    float2* dst = T2 + ((size_t)((b*NROW + row)*NCOL)) * CC;
    #pragma unroll
    for (int k = 0; k < 2; k++) {
        int off = bjL + 16*k;
        int col = base + off;
        if (off < cnt) dst[col*CC + c] = acc[k];
    }
}

// K_M: per-site 16->32 complex matvec; negative-s rows read the conj mirror.
__global__ __launch_bounds__(256) void k_mix(
        const float2* __restrict__ T2, const float2* __restrict__ KQ,
        float2* __restrict__ M2) {
    int site = blockIdx.x;            // bi*68 + bj
    int bi = site / NBI, bj = site - bi*NBI;
    int tid = threadIdx.x;
    int b = tid >> 5;                 // 8 groups of 32 lanes
    int g = tid & 31;
    int row, col;
    bool cj;
    if (bi >= 34) { row = bi - 34; col = bj;      cj = false; }
    else          { row = 34 - bi; col = 68 - bj; cj = true;  }
    const float2* x  = T2 + ((size_t)(b*NROW + row) * NCOL + col) * CC;
    const float2* kq = KQ + (size_t)site * (CC*FF);
    float sgn = cj ? -1.f : 1.f;
    float2 acc = make_float2(0.f, 0.f);
    #pragma unroll
    for (int cp = 0; cp < CC; cp++) {
        float2 xv = x[cp];
        xv.y *= sgn;
        float2 kv = kq[cp*FF + g];
        acc.x += xv.x*kv.x - xv.y*kv.y;
        acc.y += xv.x*kv.y + xv.y*kv.x;
    }
    M2[((size_t)b * (NBI*NBI) + site) * FF + g] = acc;
}

// K_E2: inverse DFT over W — LDS-broadcast + RADIX-4 over y, single-stage.
// One 384-thread block per (bi,b): stages the [68][32] M2 slice once.
// Thread = (ty 0..47, gq 0..7): y = ty, 4 g; radix-4 classes give
// y, y+48, y+96, y+144.  M3 layout [b][y][bi][g].
__global__ __launch_bounds__(384) void k_idft_w(
        const float2* __restrict__ M2, float2* __restrict__ M3) {
    int bi = blockIdx.x;
    int b  = blockIdx.y;
    int tid = threadIdx.x;
    int gq = tid & 7;                    // 0..7
    int ty = tid >> 3;                   // 0..47
    int g0 = gq * 4;
    int y  = ty;                         // [0,48)
    __shared__ float2 tl[192];
    __shared__ __align__(16) float2 m2s[NBI][FF];   // 17.4 KB
    build_twiddles(tl, tid);
    {
        const float4* src = reinterpret_cast<const float4*>(
            M2 + ((size_t)b*(NBI*NBI) + (size_t)bi*NBI) * FF);
        float4* dst = reinterpret_cast<float4*>(&m2s[0][0]);
        for (int e = tid; e < NBI*FF/2; e += 384) dst[e] = src[e];
    }
    __syncthreads();
    float2 tw = tl[(158*y) % 192];       // e^{+2pi i (-34) y/192}
    float2 rr = tl[y];                   // e^{+2pi i y/192}
    float2 zz = make_float2(0.f, 0.f);
    float2 C0[4] = {zz,zz,zz,zz};        // class 0: bj-34 ≡ 0 (mod 4)
    float2 C1[4] = {zz,zz,zz,zz};
    float2 C2[4] = {zz,zz,zz,zz};
    float2 C3[4] = {zz,zz,zz,zz};
#define IW_STEP(ROW, CL) { \
    float4 e0 = *reinterpret_cast<const float4*>(&m2s[ROW][g0]); \
    float4 e1 = *reinterpret_cast<const float4*>(&m2s[ROW][g0+2]); \
    CL[0].x += e0.x*tw.x - e0.y*tw.y;  CL[0].y += e0.x*tw.y + e0.y*tw.x; \
    CL[1].x += e0.z*tw.x - e0.w*tw.y;  CL[1].y += e0.z*tw.y + e0.w*tw.x; \
    CL[2].x += e1.x*tw.x - e1.y*tw.y;  CL[2].y += e1.x*tw.y + e1.y*tw.x; \
    CL[3].x += e1.z*tw.x - e1.w*tw.y;  CL[3].y += e1.z*tw.y + e1.w*tw.x; \
    tw = cmul(tw, rr); }
    for (int bj = 0; bj < NBI; bj += 4) {
        // bj-34 mod 4: bj+0 -> 2, bj+1 -> 3, bj+2 -> 0, bj+3 -> 1
        IW_STEP(bj,   C2)
        IW_STEP(bj+1, C3)
        IW_STEP(bj+2, C0)
        IW_STEP(bj+3, C1)
    }
#undef IW_STEP
    // Combine: out(y+48k) = sum_m i^{mk} C_m
    float2 R0[4], R1[4], R2[4], R3[4];
    #pragma unroll
    for (int k = 0; k < 4; k++) {
        float2 p = make_float2(C0[k].x + C2[k].x, C0[k].y + C2[k].y);
        float2 q = make_float2(C1[k].x + C3[k].x, C1[k].y + C3[k].y);
        float2 m = make_float2(C0[k].x - C2[k].x, C0[k].y - C2[k].y);
        float2 n = make_float2(C1[k].x - C3[k].x, C1[k].y - C3[k].y);
        R0[k] = make_float2(p.x + q.x, p.y + q.y);        // y
        R2[k] = make_float2(p.x - q.x, p.y - q.y);        // y+96
        R1[k] = make_float2(m.x - n.y, m.y + n.x);        // y+48  (m + i n)
        R3[k] = make_float2(m.x + n.y, m.y - n.x);        // y+144 (m - i n)
    }
    // M3[b][y][bi][g]
    float2* p0 = M3 + (((size_t)b*HH + y)*NBI + bi)*FF + g0;
    *reinterpret_cast<float4*>(p0)     = make_float4(R0[0].x,R0[0].y,R0[1].x,R0[1].y);
    *reinterpret_cast<float4*>(p0 + 2) = make_float4(R0[2].x,R0[2].y,R0[3].x,R0[3].y);
    float2* p1 = M3 + (((size_t)b*HH + y + 48)*NBI + bi)*FF + g0;
    *reinterpret_cast<float4*>(p1)     = make_float4(R1[0].x,R1[0].y,R1[1].x,R1[1].y);
    *reinterpret_cast<float4*>(p1 + 2) = make_float4(R1[2].x,R1[2].y,R1[3].x,R1[3].y);
    float2* p2 = M3 + (((size_t)b*HH + y + 96)*NBI + bi)*FF + g0;
    *reinterpret_cast<float4*>(p2)     = make_float4(R2[0].x,R2[0].y,R2[1].x,R2[1].y);
    *reinterpret_cast<float4*>(p2 + 2) = make_float4(R2[2].x,R2[2].y,R2[3].x,R2[3].y);
    float2* p3 = M3 + (((size_t)b*HH + y + 144)*NBI + bi)*FF + g0;
    *reinterpret_cast<float4*>(p3)     = make_float4(R3[0].x,R3[0].y,R3[1].x,R3[1].y);
    *reinterpret_cast<float4*>(p3 + 2) = make_float4(R3[2].x,R3[2].y,R3[3].x,R3[3].y);
}

// K_E3: inverse DFT over H keeping Re only, Hermitian (s,-s) pairing AND
// radix-2 over x: even/odd-p accumulators give out(x) = E+O, out(x+96) = E-O.
// comb[p][g] = (A,B):  contribution = A*cos(2pi p x/192) - B*sin(...).
// M3 layout [b][y][bi][g]: this block's slice is one contiguous 17.4 KB read.
__global__ __launch_bounds__(256) void k_idft_h(
        const float2* __restrict__ M3, float* __restrict__ out) {
    int y = blockIdx.x;
    int b = blockIdx.y;
    int tid = threadIdx.x;
    const float2* m3s = M3 + ((size_t)b*HH + y)*NBI*FF;   // [bi][g] slice
    __shared__ float2 tl[192];
    __shared__ __align__(16) float2 comb[NROW][FF];   // (A,B) per pair, 8.96 KB
    build_twiddles(tl, tid);
    for (int e = tid; e < NROW*FF; e += 256) {
        int p = e >> 5, g = e & 31;
        float A, Bv;
        if (p == 0) {
            float2 v = m3s[34*FF + g];
            A = v.x; Bv = 0.f;
        } else if (p == 34) {
            float2 v = m3s[0*FF + g];
            A = v.x; Bv = -v.y;
        } else {
            float2 vp = m3s[(34 + p)*FF + g];
            float2 vm = m3s[(34 - p)*FF + g];
            A = vp.x + vm.x; Bv = vp.y - vm.y;
        }
        comb[p][g] = make_float2(A, Bv);
    }
    __syncthreads();
    int tx = tid >> 3;          // 0..31  (3 x-pairs per thread: x = tx*3+j)
    int tg = tid & 7;
    int g0 = tg * 4;
    float2 tw[3], rr[3];
    float ae[3][4], ao[3][4];
    #pragma unroll
    for (int j = 0; j < 3; j++) {
        int x = tx*3 + j;
        tw[j] = make_float2(1.f, 0.f);   // angle p=0
        rr[j] = tl[x];                   // e^{+2pi i x/192} per p step
        #pragma unroll
        for (int q = 0; q < 4; q++) { ae[j][q] = 0.f; ao[j][q] = 0.f; }
    }
    for (int p = 0; p < 34; p += 2) {
        float4 f0 = *reinterpret_cast<const float4*>(&comb[p][g0]);     // A0,B0,A1,B1
        float4 f1 = *reinterpret_cast<const float4*>(&comb[p][g0+2]);   // A2,B2,A3,B3
        #pragma unroll
        for (int j = 0; j < 3; j++) {
            float2 t = tw[j];
            ae[j][0] += f0.x*t.x - f0.y*t.y;
            ae[j][1] += f0.z*t.x - f0.w*t.y;
            ae[j][2] += f1.x*t.x - f1.y*t.y;
            ae[j][3] += f1.z*t.x - f1.w*t.y;
            tw[j] = cmul(t, rr[j]);
        }
        float4 h0 = *reinterpret_cast<const float4*>(&comb[p+1][g0]);
        float4 h1 = *reinterpret_cast<const float4*>(&comb[p+1][g0+2]);
        #pragma unroll
        for (int j = 0; j < 3; j++) {
            float2 t = tw[j];
            ao[j][0] += h0.x*t.x - h0.y*t.y;
            ao[j][1] += h0.z*t.x - h0.w*t.y;
            ao[j][2] += h1.x*t.x - h1.y*t.y;
            ao[j][3] += h1.z*t.x - h1.w*t.y;
            tw[j] = cmul(t, rr[j]);
        }
    }
    {   // tail p = 34 (even)
        float4 f0 = *reinterpret_cast<const float4*>(&comb[34][g0]);
        float4 f1 = *reinterpret_cast<const float4*>(&comb[34][g0+2]);
        #pragma unroll
        for (int j = 0; j < 3; j++) {
            float2 t = tw[j];
            ae[j][0] += f0.x*t.x - f0.y*t.y;
            ae[j][1] += f0.z*t.x - f0.w*t.y;
            ae[j][2] += f1.x*t.x - f1.y*t.y;
            ae[j][3] += f1.z*t.x - f1.w*t.y;
        }
    }
    #pragma unroll
    for (int j = 0; j < 3; j++) {
        int x = tx*3 + j;
        float4 oA, oB;
        oA.x = (ae[j][0]+ao[j][0])*SCALE; oA.y = (ae[j][1]+ao[j][1])*SCALE;
        oA.z = (ae[j][2]+ao[j][2])*SCALE; oA.w = (ae[j][3]+ao[j][3])*SCALE;
        oB.x = (ae[j][0]-ao[j][0])*SCALE; oB.y = (ae[j][1]-ao[j][1])*SCALE;
        oB.z = (ae[j][2]-ao[j][2])*SCALE; oB.w = (ae[j][3]-ao[j][3])*SCALE;
        *reinterpret_cast<float4*>(&out[(((size_t)(b*HH + x)) * WW + y) * FF + g0]) = oA;
        *reinterpret_cast<float4*>(&out[(((size_t)(b*HH + x + 96)) * WW + y) * FF + g0]) = oB;
    }
}

extern "C" void kernel_launch(void* const* d_in, const int* in_sizes, int n_in,
                              void* d_out, int out_size, void* d_ws, size_t ws_size,
                              hipStream_t stream) {
    const float* in = (const float*)d_in[0];
    const float* kr = (const float*)d_in[1];
    const float* ki = (const float*)d_in[2];
    float* out = (float*)d_out;
    char* ws = (char*)d_ws;
    float2* KQ  = (float2*)(ws + OFF_KQ);
    float2* T1  = (float2*)(ws + OFF_T1);
    float2* T2  = (float2*)(ws + OFF_T2);
    float2* M2  = (float2*)(ws + OFF_M2);
    float2* M3  = (float2*)(ws + OFF_M3);

    k_front <<<dim3(NDFTH + NBI*NBI), 256, 0, stream>>>(in, kr, ki, KQ, T1);
    k_dft_w <<<dim3(NROW, BB, 4), 256, 0, stream>>>(T1, T2);
    k_mix   <<<NBI*NBI, 256, 0, stream>>>(T2, KQ, M2);
    k_idft_w<<<dim3(NBI, BB), 384, 0, stream>>>(M2, M3);
    k_idft_h<<<dim3(HH, BB), 256, 0, stream>>>(M3, out);
}

// Round 20
// 106.763 us; speedup vs baseline: 1.6359x; 1.0419x over previous
//
#include <hip/hip_runtime.h>
#include <math.h>

#ifndef M_PI
#define M_PI 3.14159265358979323846
#endif

// Problem constants
#define HH 192
#define WW 192
#define CC 16
#define FF 32
#define BB 8
#define NBI 68        // active frequency box per spatial axis (freqs -34..33)
#define NROW 35       // computed H-spectrum rows: s = 0..34 (rest by conj symmetry)
#define NCOL 69       // computed W-spectrum cols: sj = -34..34 (col = sj+34)
#define ROW0 62       // first centered (pre-fftshift) row of the mask box
#define MASK_T 4560   // (2i-191)^2 + (2j-191)^2 <= 4560  <=>  d/dmax < 0.25 (exact)
#define NWC (WW*CC)   // 3072
#define SCALE (1.0f/1179648.0f)   // 1/(192*192*32) ifft normalization
#define NDFTH 576     // dft_h blocks in k_front — FIRST in grid (longest-job-first)

// Workspace layout (bytes). ws_size = 256 MiB; fully de-aliased.
// Peak = 71,388,160 B (M2 slot now unused; layout kept stable).
#define OFF_KQ   4096ull        // 68*68*16*32 float2 = 18,939,904 -> ends 18,944,000
#define OFF_T1   18944000ull    // 2 * 8*35*3072 float2 = 13,762,560 -> ends 32,706,560
#define OFF_T2   32706560ull    // 8*35*69*16 float2 = 2,472,960 -> ends 35,179,520
#define OFF_M3   44649472ull    // 8*192*68*32 float2 = 26,738,688 -> ends 71,388,160
#define T1PART   (BB*NROW*NWC)  // float2 elems per h-quad partial (860,160)

__device__ __forceinline__ float2 cmul(float2 a, float2 b) {
    return make_float2(a.x*b.x - a.y*b.y, a.x*b.y + a.y*b.x);
}

// Build the 192-root twiddle table in LDS: tl[t] = e^{+2pi i t/192}.
// Table error ~1e-7 (sincosf) — negligible vs fp32 recurrence error.
__device__ __forceinline__ void build_twiddles(float2* tl, int tid) {
    if (tid < 192) {
        float th = (float)(2.0 * M_PI / 192.0) * (float)tid;
        float s, c;
        sincosf(th, &s, &c);
        tl[tid] = make_float2(c, s);
    }
}

// K_FRONT: blocks [0, NDFTH) do the partial forward DFT over H (radix-4,
// 4 rows x 3 wc per thread — the VGPR-64 shape); blocks [NDFTH, +68*68)
// densify the weights into KQ with RADIX-4 DFT16/iDFT32 (inner loops 4 and 8).
__global__ __launch_bounds__(256) void k_front(
        const float* __restrict__ in, const float* __restrict__ kr,
        const float* __restrict__ ki, float2* __restrict__ KQ,
        float2* __restrict__ T1) {
    int tid = threadIdx.x;
    __shared__ float2 tl[192];
    build_twiddles(tl, tid);
    __syncthreads();

    if (blockIdx.x < NDFTH) {
        // ---- dft_h (radix-4 over h): T1(s) = sum_{h<48} v_{s mod 4}(h) e^{-2pi i s h/192}
        int idx = blockIdx.x;             // 0..575
        int b   = idx / 72;
        int rem = idx - b*72;
        int bg  = rem >> 3;               // 0..8, 4 rows each
        int zc  = rem & 7;                // quarter*2 + part
        int z   = zc >> 1;
        int part = zc & 1;
        int h0 = part * 24;
        const float* inb = in + (size_t)b * HH * NWC;
        int wc0 = z * 768 + tid;
        float2 tw[4], r[4];
        #pragma unroll
        for (int u = 0; u < 4; u++) {
            int row = bg*4 + u;
            int s = row < NROW ? row : 0;
            float2 tv = tl[s];
            r[u] = make_float2(tv.x, -tv.y);          // e^{-2pi i s/192}
            float2 t0 = tl[(s*h0) % 192];
            tw[u] = make_float2(t0.x, -t0.y);         // e^{-2pi i s h0/192}
        }
        float2 acc[4][3];
        #pragma unroll
        for (int u = 0; u < 4; u++)
            #pragma unroll
            for (int k = 0; k < 3; k++) acc[u][k] = make_float2(0.f, 0.f);
        for (int h = h0; h < h0 + 24; h++) {
            const float* p0 = inb + (size_t)h * NWC + wc0;
            const float* p1 = p0 + 48*NWC;
            const float* p2 = p0 + 96*NWC;
            const float* p3 = p0 + 144*NWC;
            float a0=p0[0], a1=p0[256], a2=p0[512];
            float e0=p1[0], e1=p1[256], e2=p1[512];
            float c0=p2[0], c1=p2[256], c2=p2[512];
            float d0=p3[0], d1=p3[256], d2=p3[512];
            float t0_0=a0+c0, t1_0=e0+d0, t2_0=a0-c0, t3_0=e0-d0;
            float t0_1=a1+c1, t1_1=e1+d1, t2_1=a1-c1, t3_1=e1-d1;
            float t0_2=a2+c2, t1_2=e2+d2, t2_2=a2-c2, t3_2=e2-d2;
            float v0_0=t0_0+t1_0, v2_0=t0_0-t1_0;
            float v0_1=t0_1+t1_1, v2_1=t0_1-t1_1;
            float v0_2=t0_2+t1_2, v2_2=t0_2-t1_2;
            acc[0][0].x += v0_0*tw[0].x; acc[0][0].y += v0_0*tw[0].y;
            acc[0][1].x += v0_1*tw[0].x; acc[0][1].y += v0_1*tw[0].y;
            acc[0][2].x += v0_2*tw[0].x; acc[0][2].y += v0_2*tw[0].y;
            tw[0] = cmul(tw[0], r[0]);
            acc[1][0].x += t2_0*tw[1].x + t3_0*tw[1].y; acc[1][0].y += t2_0*tw[1].y - t3_0*tw[1].x;
            acc[1][1].x += t2_1*tw[1].x + t3_1*tw[1].y; acc[1][1].y += t2_1*tw[1].y - t3_1*tw[1].x;
            acc[1][2].x += t2_2*tw[1].x + t3_2*tw[1].y; acc[1][2].y += t2_2*tw[1].y - t3_2*tw[1].x;
            tw[1] = cmul(tw[1], r[1]);
            acc[2][0].x += v2_0*tw[2].x; acc[2][0].y += v2_0*tw[2].y;
            acc[2][1].x += v2_1*tw[2].x; acc[2][1].y += v2_1*tw[2].y;
            acc[2][2].x += v2_2*tw[2].x; acc[2][2].y += v2_2*tw[2].y;
            tw[2] = cmul(tw[2], r[2]);
            acc[3][0].x += t2_0*tw[3].x - t3_0*tw[3].y; acc[3][0].y += t2_0*tw[3].y + t3_0*tw[3].x;
            acc[3][1].x += t2_1*tw[3].x - t3_1*tw[3].y; acc[3][1].y += t2_1*tw[3].y + t3_1*tw[3].x;
            acc[3][2].x += t2_2*tw[3].x - t3_2*tw[3].y; acc[3][2].y += t2_2*tw[3].y + t3_2*tw[3].x;
            tw[3] = cmul(tw[3], r[3]);
        }
        #pragma unroll
        for (int u = 0; u < 4; u++) {
            int row = bg*4 + u;
            if (row < NROW) {
                float2* o = T1 + (size_t)part * T1PART + ((size_t)(b*NROW + row)) * NWC + wc0;
                o[0] = acc[u][0]; o[256] = acc[u][1]; o[512] = acc[u][2];
            }
        }
    } else {
        // ---- densify (radix-4 on both small DFTs)
        int blk = blockIdx.x - NDFTH;         // bi*68 + bj
        int bi = blk / NBI, bj = blk - bi*NBI;
        float2* KQo = KQ + (size_t)blk * (CC*FF);
        int a = 2*(ROW0+bi) - 191;
        int bc = 2*(ROW0+bj) - 191;
        bool masked = (a*a + bc*bc) <= MASK_T;   // block-uniform
        if (!masked) {
            for (int e = tid; e < CC*FF; e += 256) KQo[e] = make_float2(0.f, 0.f);
            return;
        }
        __shared__ float2 Kc[CC][FF+1];
        __shared__ float2 VA[4][4][FF];     // [m][c0][f]
        __shared__ float2 Kt[CC][FF+1];
        __shared__ float2 WB[CC][8][4];     // [cp][f0][m]
        __shared__ int cnts[NBI];
        __shared__ int rank_s;
        if (tid < NBI) {
            int ii = ROW0 + tid;
            int aa = 2*ii - 191;
            int rem = MASK_T - aa*aa;
            int q = (int)sqrtf((float)rem);
            while ((q+1)*(q+1) <= rem) q++;
            while (q > 0 && q*q > rem) q--;
            cnts[tid] = ((191 + q) >> 1) - ((192 - q) >> 1) + 1;
        }
        __syncthreads();
        if (tid == 0) {
            int acc = 0;
            for (int i = 0; i < bi; i++) acc += cnts[i];
            int ii = ROW0 + bi;
            int aa = 2*ii - 191;
            int rem = MASK_T - aa*aa;
            int q = (int)sqrtf((float)rem);
            while ((q+1)*(q+1) <= rem) q++;
            while (q > 0 && q*q > rem) q--;
            rank_s = acc + (ROW0 + bj) - ((192 - q) >> 1);
        }
        __syncthreads();
        size_t base = (size_t)rank_s * (CC*FF);
        for (int e = tid; e < CC*FF; e += 256)
            Kc[e>>5][e&31] = make_float2(kr[base+e], ki[base+e]);
        __syncthreads();
        if (tid < 128) {        // fill A: radix-4 precombine over c
            int c0 = tid >> 5, f = tid & 31;
            float2 K0 = Kc[c0][f], K1 = Kc[c0+4][f], K2 = Kc[c0+8][f], K3 = Kc[c0+12][f];
            float Px = K0.x+K2.x, Py = K0.y+K2.y;
            float Mx = K0.x-K2.x, My = K0.y-K2.y;
            float Qx = K1.x+K3.x, Qy = K1.y+K3.y;
            float Nx = K1.x-K3.x, Ny = K1.y-K3.y;
            VA[0][c0][f] = make_float2(Px+Qx, Py+Qy);
            VA[2][c0][f] = make_float2(Px-Qx, Py-Qy);
            VA[1][c0][f] = make_float2(Mx+Ny, My-Nx);   // M - iN
            VA[3][c0][f] = make_float2(Mx-Ny, My+Nx);   // M + iN
        }
        __syncthreads();
        #pragma unroll
        for (int rep = 0; rep < 2; rep++) {     // Kt: 4-tap inner loop
            int idx = tid + rep*256;
            int cp = idx >> 5, f = idx & 31;
            int m = cp & 3;
            float2 acc = make_float2(0.f, 0.f);
            #pragma unroll
            for (int c0 = 0; c0 < 4; c0++) {
                float2 w = tl[(12*c0*cp) % 192];
                float2 v = VA[m][c0][f];
                acc.x += v.x*w.x + v.y*w.y;     // v * conj(w)
                acc.y += v.y*w.x - v.x*w.y;
            }
            Kt[cp][f] = acc;
        }
        __syncthreads();
        if (tid < 128) {        // fill B: radix-4 precombine over f
            int cp = tid >> 3, f0 = tid & 7;
            float2 T0 = Kt[cp][f0], T1v = Kt[cp][f0+8], T2 = Kt[cp][f0+16], T3 = Kt[cp][f0+24];
            float Px = T0.x+T2.x, Py = T0.y+T2.y;
            float Mx = T0.x-T2.x, My = T0.y-T2.y;
            float Qx = T1v.x+T3.x, Qy = T1v.y+T3.y;
            float Nx = T1v.x-T3.x, Ny = T1v.y-T3.y;
            WB[cp][f0][0] = make_float2(Px+Qx, Py+Qy);
            WB[cp][f0][2] = make_float2(Px-Qx, Py-Qy);
            WB[cp][f0][1] = make_float2(Mx-Ny, My+Nx);   // M + iN
            WB[cp][f0][3] = make_float2(Mx+Ny, My-Nx);   // M - iN
        }
        __syncthreads();
        #pragma unroll
        for (int rep = 0; rep < 2; rep++) {     // KQ: 8-tap inner loop
            int idx = tid + rep*256;
            int cp = idx >> 5, g = idx & 31;
            int m = g & 3;
            float2 acc = make_float2(0.f, 0.f);
            #pragma unroll
            for (int f0 = 0; f0 < 8; f0++) {
                float2 w = tl[(6*f0*g) % 192];
                float2 v = WB[cp][f0][m];
                acc.x += v.x*w.x - v.y*w.y;     // v * w
                acc.y += v.x*w.y + v.y*w.x;
            }
            KQo[cp*FF + g] = acc;
        }
    }
}

// K_B: partial forward DFT over W, radix-2 over w:
// T2(col) = sum_{w=0}^{95} (S[w] +- S[w+96]) e^{-2pi i sj w/192}, class by parity(sj).
// Column dim split 4-ways across blockIdx.z for occupancy.
__global__ __launch_bounds__(256) void k_dft_w(
        const float2* __restrict__ T1, float2* __restrict__ T2) {
    int row = blockIdx.x;             // 0..34
    int b   = blockIdx.y;
    int q   = blockIdx.z;             // col quarter: bases 0,17,35,52
    const int qbase[4] = {0, 17, 35, 52};
    const int qcnt[4]  = {17, 18, 17, 17};
    int base = qbase[q], cnt = qcnt[q];
    int tid = threadIdx.x;
    __shared__ float2 tl[192];
    __shared__ float2 shp[96][CC];    // 12 KB  (S[w] + S[w+96])
    __shared__ float2 shm[96][CC];    // 12 KB  (S[w] - S[w+96])
    build_twiddles(tl, tid);
    const float2* src = T1 + ((size_t)(b*NROW + row)) * NWC;
    for (int e = tid; e < 96*CC; e += 256) {
        float2 a0 = src[e];
        float2 a1 = src[e + T1PART];
        float2 b0 = src[e + 96*CC];
        float2 b1 = src[e + 96*CC + T1PART];
        float Sx = a0.x + a1.x, Sy = a0.y + a1.y;
        float Tx = b0.x + b1.x, Ty = b0.y + b1.y;
        shp[e>>4][e&15] = make_float2(Sx + Tx, Sy + Ty);
        shm[e>>4][e&15] = make_float2(Sx - Tx, Sy - Ty);
    }
    __syncthreads();
    int c = tid >> 4;                 // 0..15
    int bjL = tid & 15;               // 0..15
    const float2* shsel = ((base + bjL) & 1) ? &shm[0][0] : &shp[0][0];
    float2 tw[2], r[2], acc[2];
    #pragma unroll
    for (int k = 0; k < 2; k++) {
        int off = bjL + 16*k;
        int col = base + off;
        bool valid = off < cnt;
        int sj = (valid ? col : 34) - 34;
        tw[k] = make_float2(1.f, 0.f);
        acc[k] = make_float2(0.f, 0.f);
        int ts = ((sj % 192) + 192) % 192;
        float2 tv = tl[ts];
        r[k] = make_float2(tv.x, -tv.y);
    }
    for (int w = 0; w < 96; w++) {
        float2 av = shsel[w*CC + c];
        #pragma unroll
        for (int k = 0; k < 2; k++) {
            acc[k].x += av.x*tw[k].x - av.y*tw[k].y;
            acc[k].y += av.x*tw[k].y + av.y*tw[k].x;
            tw[k] = cmul(tw[k], r[k]);
        }
    }
    float2* dst = T2 + ((size_t)((b*NROW + row)*NCOL)) * CC;
    #pragma unroll
    for (int k = 0; k < 2; k++) {
        int off = bjL + 16*k;
        int col = base + off;
        if (off < cnt) dst[col*CC + c] = acc[k];
    }
}

// K_E2 (fused mix + inverse-W): one 384-thread block per (bi,b).
// Phase 0: stage mirrored/conjugated T2 slice (8.7 KB).
// Phase 1: m2s[bj][g] = sum_cp t2s[bj][cp] * KQ[bi*68+bj][cp][g]  (in LDS).
// Phase 2: LDS-broadcast radix-4 inverse DFT over y (unchanged).
// M3 layout [b][y][bi][g].
__global__ __launch_bounds__(384) void k_idft_w(
        const float2* __restrict__ T2, const float2* __restrict__ KQ,
        float2* __restrict__ M3) {
    int bi = blockIdx.x;
    int b  = blockIdx.y;
    int tid = threadIdx.x;
    int gq = tid & 7;                    // 0..7
    int ty = tid >> 3;                   // 0..47
    int g0 = gq * 4;
    int y  = ty;                         // [0,48)
    __shared__ float2 tl[192];
    __shared__ __align__(16) float2 t2s[NBI][CC];   // 8.7 KB
    __shared__ __align__(16) float2 m2s[NBI][FF];   // 17.4 KB
    build_twiddles(tl, tid);
    // Phase 0: T2 slice with Hermitian mirror (bi branch is block-uniform)
    for (int e = tid; e < NBI*CC; e += 384) {
        int bj = e >> 4, cp = e & 15;
        float2 v;
        if (bi >= 34) {
            v = T2[((size_t)(b*NROW + (bi-34))*NCOL + bj)*CC + cp];
        } else {
            v = T2[((size_t)(b*NROW + (34-bi))*NCOL + (68-bj))*CC + cp];
            v.y = -v.y;
        }
        t2s[bj][cp] = v;
    }
    __syncthreads();
    // Phase 1: per-site 16->32 complex matvec into LDS
    const float2* kqb = KQ + (size_t)(bi*NBI) * (CC*FF);
    for (int e = tid; e < NBI*FF; e += 384) {
        int bj = e >> 5, g = e & 31;
        const float2* kq = kqb + (size_t)bj*(CC*FF) + g;
        float2 acc = make_float2(0.f, 0.f);
        #pragma unroll
        for (int cp = 0; cp < CC; cp++) {
            float2 xv = t2s[bj][cp];
            float2 kv = kq[cp*FF];
            acc.x += xv.x*kv.x - xv.y*kv.y;
            acc.y += xv.x*kv.y + xv.y*kv.x;
        }
        m2s[bj][g] = acc;
    }
    __syncthreads();
    // Phase 2: radix-4 inverse DFT over y
    float2 tw = tl[(158*y) % 192];       // e^{+2pi i (-34) y/192}
    float2 rr = tl[y];                   // e^{+2pi i y/192}
    float2 zz = make_float2(0.f, 0.f);
    float2 C0[4] = {zz,zz,zz,zz};        // class 0: bj-34 ≡ 0 (mod 4)
    float2 C1[4] = {zz,zz,zz,zz};
    float2 C2[4] = {zz,zz,zz,zz};
    float2 C3[4] = {zz,zz,zz,zz};
#define IW_STEP(ROW, CL) { \
    float4 e0 = *reinterpret_cast<const float4*>(&m2s[ROW][g0]); \
    float4 e1 = *reinterpret_cast<const float4*>(&m2s[ROW][g0+2]); \
    CL[0].x += e0.x*tw.x - e0.y*tw.y;  CL[0].y += e0.x*tw.y + e0.y*tw.x; \
    CL[1].x += e0.z*tw.x - e0.w*tw.y;  CL[1].y += e0.z*tw.y + e0.w*tw.x; \
    CL[2].x += e1.x*tw.x - e1.y*tw.y;  CL[2].y += e1.x*tw.y + e1.y*tw.x; \
    CL[3].x += e1.z*tw.x - e1.w*tw.y;  CL[3].y += e1.z*tw.y + e1.w*tw.x; \
    tw = cmul(tw, rr); }
    for (int bj = 0; bj < NBI; bj += 4) {
        // bj-34 mod 4: bj+0 -> 2, bj+1 -> 3, bj+2 -> 0, bj+3 -> 1
        IW_STEP(bj,   C2)
        IW_STEP(bj+1, C3)
        IW_STEP(bj+2, C0)
        IW_STEP(bj+3, C1)
    }
#undef IW_STEP
    // Combine: out(y+48k) = sum_m i^{mk} C_m
    float2 R0[4], R1[4], R2[4], R3[4];
    #pragma unroll
    for (int k = 0; k < 4; k++) {
        float2 p = make_float2(C0[k].x + C2[k].x, C0[k].y + C2[k].y);
        float2 q = make_float2(C1[k].x + C3[k].x, C1[k].y + C3[k].y);
        float2 m = make_float2(C0[k].x - C2[k].x, C0[k].y - C2[k].y);
        float2 n = make_float2(C1[k].x - C3[k].x, C1[k].y - C3[k].y);
        R0[k] = make_float2(p.x + q.x, p.y + q.y);        // y
        R2[k] = make_float2(p.x - q.x, p.y - q.y);        // y+96
        R1[k] = make_float2(m.x - n.y, m.y + n.x);        // y+48  (m + i n)
        R3[k] = make_float2(m.x + n.y, m.y - n.x);        // y+144 (m - i n)
    }
    // M3[b][y][bi][g]
    float2* p0 = M3 + (((size_t)b*HH + y)*NBI + bi)*FF + g0;
    *reinterpret_cast<float4*>(p0)     = make_float4(R0[0].x,R0[0].y,R0[1].x,R0[1].y);
    *reinterpret_cast<float4*>(p0 + 2) = make_float4(R0[2].x,R0[2].y,R0[3].x,R0[3].y);
    float2* p1 = M3 + (((size_t)b*HH + y + 48)*NBI + bi)*FF + g0;
    *reinterpret_cast<float4*>(p1)     = make_float4(R1[0].x,R1[0].y,R1[1].x,R1[1].y);
    *reinterpret_cast<float4*>(p1 + 2) = make_float4(R1[2].x,R1[2].y,R1[3].x,R1[3].y);
    float2* p2 = M3 + (((size_t)b*HH + y + 96)*NBI + bi)*FF + g0;
    *reinterpret_cast<float4*>(p2)     = make_float4(R2[0].x,R2[0].y,R2[1].x,R2[1].y);
    *reinterpret_cast<float4*>(p2 + 2) = make_float4(R2[2].x,R2[2].y,R2[3].x,R2[3].y);
    float2* p3 = M3 + (((size_t)b*HH + y + 144)*NBI + bi)*FF + g0;
    *reinterpret_cast<float4*>(p3)     = make_float4(R3[0].x,R3[0].y,R3[1].x,R3[1].y);
    *reinterpret_cast<float4*>(p3 + 2) = make_float4(R3[2].x,R3[2].y,R3[3].x,R3[3].y);
}

// K_E3: inverse DFT over H keeping Re only, Hermitian (s,-s) pairing AND
// radix-2 over x: even/odd-p accumulators give out(x) = E+O, out(x+96) = E-O.
// M3 layout [b][y][bi][g]: this block's slice is one contiguous 17.4 KB read.
__global__ __launch_bounds__(256) void k_idft_h(
        const float2* __restrict__ M3, float* __restrict__ out) {
    int y = blockIdx.x;
    int b = blockIdx.y;
    int tid = threadIdx.x;
    const float2* m3s = M3 + ((size_t)b*HH + y)*NBI*FF;   // [bi][g] slice
    __shared__ float2 tl[192];
    __shared__ __align__(16) float2 comb[NROW][FF];   // (A,B) per pair, 8.96 KB
    build_twiddles(tl, tid);
    for (int e = tid; e < NROW*FF; e += 256) {
        int p = e >> 5, g = e & 31;
        float A, Bv;
        if (p == 0) {
            float2 v = m3s[34*FF + g];
            A = v.x; Bv = 0.f;
        } else if (p == 34) {
            float2 v = m3s[0*FF + g];
            A = v.x; Bv = -v.y;
        } else {
            float2 vp = m3s[(34 + p)*FF + g];
            float2 vm = m3s[(34 - p)*FF + g];
            A = vp.x + vm.x; Bv = vp.y - vm.y;
        }
        comb[p][g] = make_float2(A, Bv);
    }
    __syncthreads();
    int tx = tid >> 3;          // 0..31  (3 x-pairs per thread: x = tx*3+j)
    int tg = tid & 7;
    int g0 = tg * 4;
    float2 tw[3], rr[3];
    float ae[3][4], ao[3][4];
    #pragma unroll
    for (int j = 0; j < 3; j++) {
        int x = tx*3 + j;
        tw[j] = make_float2(1.f, 0.f);   // angle p=0
        rr[j] = tl[x];                   // e^{+2pi i x/192} per p step
        #pragma unroll
        for (int q = 0; q < 4; q++) { ae[j][q] = 0.f; ao[j][q] = 0.f; }
    }
    for (int p = 0; p < 34; p += 2) {
        float4 f0 = *reinterpret_cast<const float4*>(&comb[p][g0]);     // A0,B0,A1,B1
        float4 f1 = *reinterpret_cast<const float4*>(&comb[p][g0+2]);   // A2,B2,A3,B3
        #pragma unroll
        for (int j = 0; j < 3; j++) {
            float2 t = tw[j];
            ae[j][0] += f0.x*t.x - f0.y*t.y;
            ae[j][1] += f0.z*t.x - f0.w*t.y;
            ae[j][2] += f1.x*t.x - f1.y*t.y;
            ae[j][3] += f1.z*t.x - f1.w*t.y;
            tw[j] = cmul(t, rr[j]);
        }
        float4 h0 = *reinterpret_cast<const float4*>(&comb[p+1][g0]);
        float4 h1 = *reinterpret_cast<const float4*>(&comb[p+1][g0+2]);
        #pragma unroll
        for (int j = 0; j < 3; j++) {
            float2 t = tw[j];
            ao[j][0] += h0.x*t.x - h0.y*t.y;
            ao[j][1] += h0.z*t.x - h0.w*t.y;
            ao[j][2] += h1.x*t.x - h1.y*t.y;
            ao[j][3] += h1.z*t.x - h1.w*t.y;
            tw[j] = cmul(t, rr[j]);
        }
    }
    {   // tail p = 34 (even)
        float4 f0 = *reinterpret_cast<const float4*>(&comb[34][g0]);
        float4 f1 = *reinterpret_cast<const float4*>(&comb[34][g0+2]);
        #pragma unroll
        for (int j = 0; j < 3; j++) {
            float2 t = tw[j];
            ae[j][0] += f0.x*t.x - f0.y*t.y;
            ae[j][1] += f0.z*t.x - f0.w*t.y;
            ae[j][2] += f1.x*t.x - f1.y*t.y;
            ae[j][3] += f1.z*t.x - f1.w*t.y;
        }
    }
    #pragma unroll
    for (int j = 0; j < 3; j++) {
        int x = tx*3 + j;
        float4 oA, oB;
        oA.x = (ae[j][0]+ao[j][0])*SCALE; oA.y = (ae[j][1]+ao[j][1])*SCALE;
        oA.z = (ae[j][2]+ao[j][2])*SCALE; oA.w = (ae[j][3]+ao[j][3])*SCALE;
        oB.x = (ae[j][0]-ao[j][0])*SCALE; oB.y = (ae[j][1]-ao[j][1])*SCALE;
        oB.z = (ae[j][2]-ao[j][2])*SCALE; oB.w = (ae[j][3]-ao[j][3])*SCALE;
        *reinterpret_cast<float4*>(&out[(((size_t)(b*HH + x)) * WW + y) * FF + g0]) = oA;
        *reinterpret_cast<float4*>(&out[(((size_t)(b*HH + x + 96)) * WW + y) * FF + g0]) = oB;
    }
}

extern "C" void kernel_launch(void* const* d_in, const int* in_sizes, int n_in,
                              void* d_out, int out_size, void* d_ws, size_t ws_size,
                              hipStream_t stream) {
    const float* in = (const float*)d_in[0];
    const float* kr = (const float*)d_in[1];
    const float* ki = (const float*)d_in[2];
    float* out = (float*)d_out;
    char* ws = (char*)d_ws;
    float2* KQ  = (float2*)(ws + OFF_KQ);
    float2* T1  = (float2*)(ws + OFF_T1);
    float2* T2  = (float2*)(ws + OFF_T2);
    float2* M3  = (float2*)(ws + OFF_M3);

    k_front <<<dim3(NDFTH + NBI*NBI), 256, 0, stream>>>(in, kr, ki, KQ, T1);
    k_dft_w <<<dim3(NROW, BB, 4), 256, 0, stream>>>(T1, T2);
    k_idft_w<<<dim3(NBI, BB), 384, 0, stream>>>(T2, KQ, M3);
    k_idft_h<<<dim3(HH, BB), 256, 0, stream>>>(M3, out);
}